// Round 2
// 2427.996 us; speedup vs baseline: 1.8912x; 1.8912x over previous
//
#include <hip/hip_runtime.h>
#include <cstddef>

#define Bn 32
#define Sn 512
#define Hn 512
#define Rn (Bn*Sn)
#define NLAYER 4
constexpr size_t NHe = (size_t)Rn * Hn;   // 8,388,608 elements per (B,S,H) tensor

typedef __attribute__((ext_vector_type(8))) _Float16 f16x8;
typedef __attribute__((ext_vector_type(4))) float f32x4;

__device__ __forceinline__ float sigf(float x) { return 1.f / (1.f + __expf(-x)); }
// 16B global -> LDS DMA (lane-linear dest; LDS base is wave-uniform + lane*16)
__device__ __forceinline__ void gl_lds16(const void* g, void* l) {
  __builtin_amdgcn_global_load_lds((const __attribute__((address_space(1))) void*)g,
                                   (__attribute__((address_space(3))) void*)l, 16, 0, 0);
}

// ---------------- init: h = init_h*m, c = init_c*m ----------------
__global__ void k_init(const float* __restrict__ ih, const float* __restrict__ ic,
                       const int* __restrict__ mask,
                       float* __restrict__ h, float* __restrict__ c) {
  size_t i = (size_t)blockIdx.x * blockDim.x + threadIdx.x;  // over NHe/4
  size_t n = i >> 7;
  float m = (float)mask[n];
  float4 b = ((const float4*)ih)[i];
  float4 d = ((const float4*)ic)[i];
  b.x *= m; b.y *= m; b.z *= m; b.w *= m;
  d.x *= m; d.y *= m; d.z *= m; d.w *= m;
  ((float4*)h)[i] = b; ((float4*)c)[i] = d;
}

// ---------------- mean2 (once): dh, dc ----------------
__global__ void k_mean2(const float* __restrict__ x, const float* __restrict__ y,
                        float* __restrict__ ox, float* __restrict__ oy) {
  int idx = blockIdx.x * blockDim.x + threadIdx.x;
  int b = idx >> 9, k = idx & 511;
  const float* px = x + (size_t)b * Sn * Hn + k;
  const float* py = y + (size_t)b * Sn * Hn + k;
  float sx = 0.f, sy = 0.f;
#pragma unroll 8
  for (int t = 0; t < Sn; ++t) { sx += px[(size_t)t * Hn]; sy += py[(size_t)t * Hn]; }
  ox[idx] = sx * (1.f / Sn); oy[idx] = sy * (1.f / Sn);
}

// ---------------- mean over s: two-stage, float4 ----------------
__global__ void k_mean1a(const float* __restrict__ x, float* __restrict__ part) {
  int b = blockIdx.x, sc = blockIdx.y;          // 32 x 8
  int k4 = threadIdx.x & 127;                   // float4 over 512 k
  int so = threadIdx.x >> 7;                    // 0/1
  const float4* px = (const float4*)x + ((size_t)(b * Sn + sc * 64 + so)) * 128 + k4;
  float4 s = make_float4(0.f, 0.f, 0.f, 0.f);
#pragma unroll 4
  for (int t = 0; t < 32; ++t) {
    float4 v = px[(size_t)t * 256];
    s.x += v.x; s.y += v.y; s.z += v.z; s.w += v.w;
  }
  ((float4*)part)[((size_t)(sc * 2 + so) * Bn + b) * 128 + k4] = s;
}
__global__ void k_mean1b(const float* __restrict__ part, float* __restrict__ comb) {
  int idx = blockIdx.x * blockDim.x + threadIdx.x;   // B*H/4 = 4096
  int b = idx >> 7, k4 = idx & 127;
  float4 s = make_float4(0.f, 0.f, 0.f, 0.f);
#pragma unroll
  for (int p = 0; p < 16; ++p) {
    float4 v = ((const float4*)part)[((size_t)p * Bn + b) * 128 + k4];
    s.x += v.x; s.y += v.y; s.z += v.z; s.w += v.w;
  }
  s.x *= (1.f / Sn); s.y *= (1.f / Sn); s.z *= (1.f / Sn); s.w *= (1.f / Sn);
  ((float4*)comb)[idx] = s;
}

// ---------------- small gates: gd, go, gfA ----------------
__global__ void k_gates_small(const float* __restrict__ dh, const float* __restrict__ comb,
                              const float* __restrict__ gW, const float* __restrict__ gb,
                              float* __restrict__ gd, float* __restrict__ go,
                              float* __restrict__ gfA) {
  int idx = blockIdx.x * blockDim.x + threadIdx.x;  // B*H
  int b = idx >> 9, k = idx & 511;
  const float* gW0 = gW;
  const float* gW1 = gW + 1 * Hn * Hn;
  const float* gW2 = gW + 2 * Hn * Hn;
  const float* gW3 = gW + 3 * Hn * Hn;
  const float* gW4 = gW + 4 * Hn * Hn;
  const float* dhb = dh + b * Hn;
  const float* cbp = comb + b * Hn;
  float s0 = 0.f, s1 = 0.f, s2 = 0.f, s3 = 0.f, s4 = 0.f;
#pragma unroll 4
  for (int j = 0; j < Hn; ++j) {
    float a = dhb[j], c2 = cbp[j];
    s0 += a * gW0[j * Hn + k];
    s1 += c2 * gW1[j * Hn + k];
    s2 += a * gW2[j * Hn + k];
    s3 += c2 * gW3[j * Hn + k];
    s4 += a * gW4[j * Hn + k];
  }
  gd[idx] = sigf(s0 + s1 + gb[k]);
  go[idx] = sigf(s2 + s3 + gb[Hn + k]);
  gfA[idx] = s4 + gb[2 * Hn + k];
}

// ---------------- dWd[g,b,k] = dummy_h[b,:] @ Wd[g,:,k] ----------------
__global__ void k_dWd(const float* __restrict__ dh, const float* __restrict__ Wd,
                      float* __restrict__ dWd) {
  int idx = blockIdx.x * blockDim.x + threadIdx.x;  // 8*B*H
  int k = idx & 511; int bg = idx >> 9; int b = bg & 31; int g = bg >> 5;
  const float* w = Wd + (size_t)g * Hn * Hn;
  const float* dhb = dh + b * Hn;
  float s = 0.f;
#pragma unroll 4
  for (int j = 0; j < Hn; ++j) s += dhb[j] * w[j * Hn + k];
  dWd[idx] = s;
}

// ---------------- dummy softmax: two-stage streamed ----------------
__global__ void k_dummy1(const float* __restrict__ G, const float* __restrict__ gfA,
                         const float* __restrict__ c, const int* __restrict__ mask,
                         float* __restrict__ np_, float* __restrict__ dp_) {
  int b = blockIdx.x, sc = blockIdx.y;   // 32 x 8, 512 threads
  int k = threadIdx.x;
  float gfa = gfA[(b << 9) | k];
  const float* Gp = G + ((size_t)(b * Sn + sc * 64)) * Hn + k;
  const float* cp = c + ((size_t)(b * Sn + sc * 64)) * Hn + k;
  const int* mp = mask + b * Sn + sc * 64;
  float num = 0.f, den = 0.f;
#pragma unroll 4
  for (int s = 0; s < 64; ++s) {
    float e = __expf(sigf(Gp[(size_t)s * Hn] + gfa));
    e = mp[s] ? e : 0.f;
    num += e * cp[(size_t)s * Hn];
    den += e;
  }
  np_[((size_t)sc * Bn + b) * Hn + k] = num;
  dp_[((size_t)sc * Bn + b) * Hn + k] = den;
}
__global__ void k_dummy2(const float* __restrict__ np_, const float* __restrict__ dp_,
                         const float* __restrict__ gd, const float* __restrict__ go,
                         const float* __restrict__ dc,
                         float* __restrict__ dh2, float* __restrict__ dc2) {
  int idx = blockIdx.x * blockDim.x + threadIdx.x;  // B*H
  int b = idx >> 9, k = idx & 511;
  float ed = __expf(gd[idx]);
  float num = ed * dc[idx], den = ed;
#pragma unroll
  for (int sc = 0; sc < 8; ++sc) {
    num += np_[((size_t)sc * Bn + b) * Hn + k];
    den += dp_[((size_t)sc * Bn + b) * Hn + k];
  }
  float d = num / den;
  dc2[idx] = d;
  dh2[idx] = go[idx] * tanhf(d);
}

// ---------------- weight pre-swizzle: f32 [g][k][n] -> fp16 frag-order superblocks ----------------
// Bhat superblock sb = (t*16 + nT)*16 + kcT, 8192 halfs (16KB) each.
// Interior: (((g*2 + ni)*4 + quad)*16 + l15)*8 + j ; element k=kcT*32+quad*8+j, n=nT*32+ni*16+l15
__global__ void k_convw(const float* __restrict__ Wx, const float* __restrict__ Wh,
                        const float* __restrict__ Wsm, const float* __restrict__ Wi,
                        _Float16* __restrict__ Bhat) {
  int kcT = blockIdx.x, nT = blockIdx.y, tg = blockIdx.z;  // 16,16,40
  int t = tg >> 3, g = tg & 7;
  const float* base;
  if (t == 0)      base = Wx  + (size_t)g * 262144;
  else if (t == 1) base = Wh  + (size_t)g * 524288;
  else if (t == 2) base = Wh  + (size_t)g * 524288 + 262144;
  else if (t == 3) base = Wsm + (size_t)g * 262144;
  else             base = Wi  + (size_t)g * 262144;
  size_t sbase = ((size_t)(t * 16 + nT) * 16 + kcT) * 8192 + (size_t)g * 1024;
  int lane = threadIdx.x;  // 64 threads
  for (int cch = lane; cch < 128; cch += 64) {
    int ni = cch >> 6, quad = (cch >> 4) & 3, l15 = cch & 15;
    int n = nT * 32 + ni * 16 + l15;
    int k0 = kcT * 32 + quad * 8;
    f16x8 w8;
#pragma unroll
    for (int j = 0; j < 8; ++j) w8[j] = (_Float16)base[(size_t)(k0 + j) * Hn + n];
    *(f16x8*)&Bhat[sbase + (size_t)cch * 8] = w8;
  }
}

// ---------------- gWhf pre-swizzle (once): superblock (nT4*16+kcT), 4096 halfs ----------------
// Interior: ((nj*4 + quad)*16 + l15)*8 + j ; element k=kcT*32+quad*8+j, n=nT4*128+nj*16+l15
__global__ void k_convG(const float* __restrict__ gW, _Float16* __restrict__ Ghat) {
  int kcT = blockIdx.x, nT4 = blockIdx.y;  // 16, 4
  int tid = threadIdx.x;                   // 256
  const float* w = gW + (size_t)5 * Hn * Hn;
  size_t sb = ((size_t)(nT4 * 16 + kcT)) * 4096;
#pragma unroll
  for (int half = 0; half < 2; ++half) {
    int st = half * 256 + tid;             // slot 0..511
    int nj = st >> 6, quad = (st >> 4) & 3, l15 = st & 15;
    int n = nT4 * 128 + nj * 16 + l15;
    int k0 = kcT * 32 + quad * 8;
    f16x8 w8;
#pragma unroll
    for (int j = 0; j < 8; ++j) w8[j] = (_Float16)w[(size_t)(k0 + j) * Hn + n];
    *(f16x8*)&Ghat[sb + (size_t)st * 8] = w8;
  }
}

// ---------------- A pre-convert per layer: terms 0..3 -> fp16 frag-order superblocks ----------------
// Ahat superblock sb = (t*128 + mb)*16 + kcT, 4096 halfs (8KB).
// Interior slot st = (rg*4 + quad)*16 + l15 ; element row=mb*128+rg*16+l15, k=kcT*32+quad*8+j
__global__ void k_prepA(const float* __restrict__ h, const int* __restrict__ pos,
                        _Float16* __restrict__ Ahat) {
  const int mb = blockIdx.x, kcT = blockIdx.y, t = blockIdx.z;  // 128,16,4
  const int tid = threadIdx.x;  // 256
  size_t sb = ((size_t)(t * 128 + mb) * 16 + kcT) * 4096;
#pragma unroll
  for (int half = 0; half < 2; ++half) {
    int st = half * 256 + tid;
    int rg = st >> 6, quad = (st >> 4) & 3, l15 = st & 15;
    int r = mb * 128 + rg * 16 + l15;
    int srow = r & (Sn - 1);
    int k0 = kcT * 32 + quad * 8;
    const float* base = h + (size_t)r * Hn + k0;
    float v[8];
    if (t == 0) {
#pragma unroll
      for (int j = 0; j < 8; ++j) v[j] = base[j];
    } else if (t == 1) {
#pragma unroll
      for (int j = 0; j < 8; ++j) v[j] = 0.f;
      if (srow >= 1) { const float* p = base - Hn;
#pragma unroll
        for (int j = 0; j < 8; ++j) v[j] += p[j]; }
      if (srow >= 2) { const float* p = base - 2 * Hn;
#pragma unroll
        for (int j = 0; j < 8; ++j) v[j] += p[j]; }
    } else if (t == 2) {
#pragma unroll
      for (int j = 0; j < 8; ++j) v[j] = 0.f;
      if (srow <= Sn - 2) { const float* p = base + Hn;
#pragma unroll
        for (int j = 0; j < 8; ++j) v[j] += p[j]; }
      if (srow <= Sn - 3) { const float* p = base + 2 * Hn;
#pragma unroll
        for (int j = 0; j < 8; ++j) v[j] += p[j]; }
    } else {
      int pp = pos[r];
      if (pp) {
        const float* p = h + ((size_t)((r >> 9) * Sn + pp - 1)) * Hn + k0;
#pragma unroll
        for (int j = 0; j < 8; ++j) v[j] = p[j];
      } else {
#pragma unroll
        for (int j = 0; j < 8; ++j) v[j] = 0.f;
      }
    }
    f16x8 o8;
#pragma unroll
    for (int j = 0; j < 8; ++j) o8[j] = (_Float16)v[j];
    *(f16x8*)&Ahat[sb + (size_t)st * 8] = o8;
  }
}

// word term (t=4): layer-invariant, run once
__global__ void k_prepW(const float* __restrict__ w, const int* __restrict__ mask,
                        _Float16* __restrict__ Ahat) {
  const int mb = blockIdx.x, kcT = blockIdx.y;  // 128,16
  const int tid = threadIdx.x;
  size_t sb = ((size_t)(4 * 128 + mb) * 16 + kcT) * 4096;
#pragma unroll
  for (int half = 0; half < 2; ++half) {
    int st = half * 256 + tid;
    int rg = st >> 6, quad = (st >> 4) & 3, l15 = st & 15;
    int r = mb * 128 + rg * 16 + l15;
    int k0 = kcT * 32 + quad * 8;
    float mf = (float)mask[r];
    const float* base = w + (size_t)r * Hn + k0;
    f16x8 o8;
#pragma unroll
    for (int j = 0; j < 8; ++j) o8[j] = (_Float16)(base[j] * mf);
    *(f16x8*)&Ahat[sb + (size_t)st * 8] = o8;
  }
}

// ---------------- G = h @ gWhf (fp16 MFMA, reuses Ahat term 0) ----------------
// BM=128, BN=128, grid (128 mb, 4 nT4), 256 threads = 4 waves; wave owns 32 rows.
__global__ __launch_bounds__(256, 3) void k_gemm1(const _Float16* __restrict__ Ahat,
                                                  const _Float16* __restrict__ Ghat,
                                                  float* __restrict__ G) {
  __shared__ _Float16 As[2][4096];
  __shared__ _Float16 Bs[2][4096];
  const int tid = threadIdx.x;
  const int mb = blockIdx.x, nT4 = blockIdx.y;
  const int lane = tid & 63, wid = tid >> 6;
  const int quad = lane >> 4, l15 = lane & 15;
  const int afo0 = (((wid * 2 + 0) * 4 + quad) * 16 + l15) * 8;
  const int afo1 = (((wid * 2 + 1) * 4 + quad) * 16 + l15) * 8;

  f32x4 acc[2][8];
#pragma unroll
  for (int mi = 0; mi < 2; ++mi)
#pragma unroll
    for (int nj = 0; nj < 8; ++nj) acc[mi][nj] = (f32x4){0.f, 0.f, 0.f, 0.f};

  auto stage = [&](int buf, int kcT) {
    const int4* sa = (const int4*)Ahat + ((size_t)(mb * 16 + kcT) << 9);
    const int4* sbp = (const int4*)Ghat + ((size_t)(nT4 * 16 + kcT) << 9);
#pragma unroll
    for (int q = 0; q < 2; ++q) {
      gl_lds16(sa + q * 256 + tid, &As[buf][(q * 256 + tid) * 8]);
      gl_lds16(sbp + q * 256 + tid, &Bs[buf][(q * 256 + tid) * 8]);
    }
  };

  stage(0, 0);
  __syncthreads();
#pragma unroll 1
  for (int kcT = 0; kcT < 16; ++kcT) {
    const int cur = kcT & 1;
    if (kcT < 15) stage(cur ^ 1, kcT + 1);
    f16x8 a0 = *(const f16x8*)&As[cur][afo0];
    f16x8 a1 = *(const f16x8*)&As[cur][afo1];
#pragma unroll
    for (int nj = 0; nj < 8; ++nj) {
      f16x8 bh = *(const f16x8*)&Bs[cur][((nj * 4 + quad) * 16 + l15) * 8];
      acc[0][nj] = __builtin_amdgcn_mfma_f32_16x16x32_f16(a0, bh, acc[0][nj], 0, 0, 0);
      acc[1][nj] = __builtin_amdgcn_mfma_f32_16x16x32_f16(a1, bh, acc[1][nj], 0, 0, 0);
    }
    __syncthreads();
  }
#pragma unroll
  for (int mi = 0; mi < 2; ++mi)
#pragma unroll
    for (int r = 0; r < 4; ++r) {
      int row = mb * 128 + wid * 32 + mi * 16 + quad * 4 + r;
      float* gp = G + (size_t)row * Hn + nT4 * 128 + l15;
#pragma unroll
      for (int nj = 0; nj < 8; ++nj) gp[nj * 16] = acc[mi][nj][r];
    }
}

// ---------------- mega GEMM: all 8 groups, 5 terms, fused gate epilogue ----------------
// BM=128, BN=32 (x8 groups), BK=32; staging = 16B global_load_lds of pre-swizzled fp16
// Ahat/Bhat superblocks, depth-1 prefetch double-buffer, ONE barrier per chunk.
__global__ __launch_bounds__(256, 2) void k_mega(
    const float* __restrict__ c,
    const _Float16* __restrict__ Ahat, const _Float16* __restrict__ Bhat,
    const int* __restrict__ pos, const int* __restrict__ mask,
    const float* __restrict__ dc, const float* __restrict__ dWd,
    const float* __restrict__ bias,
    float* __restrict__ hout, float* __restrict__ cout) {
  __shared__ _Float16 As[2][4096];   // 8KB per buffer
  __shared__ _Float16 Bs[2][8192];   // 16KB per buffer

  const int tid = threadIdx.x;
  const int id = blockIdx.x;          // 2048
  const int loc = id >> 3;            // 0..255
  const int mb = loc >> 1;            // same-mb pair adjacent -> A superblocks L2-shared
  const int nT = (id & 7) * 2 + (loc & 1);
  const int m0 = mb * 128;
  const int n0 = nT * 32;
  const int bb = m0 >> 9;             // batch index (tile spans one batch)

  const int lane = tid & 63, wid = tid >> 6;
  const int quad = lane >> 4, l15 = lane & 15;
  const int afo0 = (((wid * 2 + 0) * 4 + quad) * 16 + l15) * 8;
  const int afo1 = (((wid * 2 + 1) * 4 + quad) * 16 + l15) * 8;

  f32x4 acc[8][2][2];
#pragma unroll
  for (int g = 0; g < 8; ++g)
#pragma unroll
    for (int mi = 0; mi < 2; ++mi)
#pragma unroll
      for (int ni = 0; ni < 2; ++ni) acc[g][mi][ni] = (f32x4){0.f, 0.f, 0.f, 0.f};

  auto stage = [&](int buf, int cn) {
    const int t = cn >> 4, kcT = cn & 15;
    const int4* sa = (const int4*)Ahat + ((size_t)((t * 128 + mb) * 16 + kcT) << 9);
    const int4* sbp = (const int4*)Bhat + ((size_t)((t * 16 + nT) * 16 + kcT) << 10);
#pragma unroll
    for (int q = 0; q < 2; ++q)
      gl_lds16(sa + q * 256 + tid, &As[buf][(q * 256 + tid) * 8]);
#pragma unroll
    for (int q = 0; q < 4; ++q)
      gl_lds16(sbp + q * 256 + tid, &Bs[buf][(q * 256 + tid) * 8]);
  };

  stage(0, 0);
  __syncthreads();
#pragma unroll 1
  for (int ci = 0; ci < 80; ++ci) {
    const int cur = ci & 1;
    if (ci < 79) stage(cur ^ 1, ci + 1);   // prefetch hides under MFMA phase
    f16x8 a0 = *(const f16x8*)&As[cur][afo0];
    f16x8 a1 = *(const f16x8*)&As[cur][afo1];
#pragma unroll
    for (int g = 0; g < 8; ++g) {
#pragma unroll
      for (int ni = 0; ni < 2; ++ni) {
        f16x8 bh = *(const f16x8*)&Bs[cur][(((g * 2 + ni) * 4 + quad) * 16 + l15) * 8];
        acc[g][0][ni] = __builtin_amdgcn_mfma_f32_16x16x32_f16(a0, bh, acc[g][0][ni], 0, 0, 0);
        acc[g][1][ni] = __builtin_amdgcn_mfma_f32_16x16x32_f16(a1, bh, acc[g][1][ni], 0, 0, 0);
      }
    }
    __syncthreads();   // drains prefetch vmcnt + protects buf reuse
  }

  // ---- fused epilogue ----
  float biasr[8][2], dwdr[8][2], tdcv[2];
#pragma unroll
  for (int ni = 0; ni < 2; ++ni) {
    int col = n0 + ni * 16 + l15;
    tdcv[ni] = dc[bb * Hn + col];
#pragma unroll
    for (int g = 0; g < 8; ++g) {
      biasr[g][ni] = bias[g * Hn + col];
      dwdr[g][ni] = dWd[((size_t)g * Bn + bb) * Hn + col];
    }
  }

#pragma unroll
  for (int mi = 0; mi < 2; ++mi) {
#pragma unroll
    for (int r = 0; r < 4; ++r) {
      const int row = m0 + wid * 32 + mi * 16 + quad * 4 + r;
      const int srow = row & (Sn - 1);
      const float mf = (float)mask[row];
      const int pp = pos[row];
      const size_t rb = (size_t)row * Hn;
#pragma unroll
      for (int ni = 0; ni < 2; ++ni) {
        const int col = n0 + ni * 16 + l15;
        float cf = c[rb + col];
        float cb = 0.f, ca = 0.f;
        if (srow >= 1) cb = c[rb - Hn + col];
        if (srow >= 2) cb += c[rb - 2 * Hn + col];
        if (srow <= Sn - 2) ca = c[rb + Hn + col];
        if (srow <= Sn - 3) ca += c[rb + 2 * Hn + col];
        float sw = pp ? c[((size_t)(bb * Sn + pp - 1)) * Hn + col] : 0.f;
        float z[8];
#pragma unroll
        for (int g = 0; g < 8; ++g)
          z[g] = acc[g][mi][ni][r] + biasr[g][ni] + dwdr[g][ni];
        float e0 = __expf(sigf(z[0]));
        float e1 = __expf(sigf(z[1]));
        float e2 = __expf(sigf(z[2]));
        float e3 = __expf(sigf(z[3]));
        float e4 = __expf(sigf(z[4]));
        float e5 = __expf(sigf(z[5]));
        float inv = 1.f / (e0 + e1 + e2 + e3 + e4 + e5);
        float o = sigf(z[6]);
        float u = tanhf(z[7]);
        float cn = inv * (e0 * cb + e1 * ca + e2 * cf + e3 * tdcv[ni] + e4 * sw + e5 * u);
        cout[rb + col] = cn * mf;
        hout[rb + col] = o * tanhf(cn) * mf;
      }
    }
  }
}

extern "C" void kernel_launch(void* const* d_in, const int* in_sizes, int n_in,
                              void* d_out, int out_size, void* d_ws, size_t ws_size,
                              hipStream_t stream) {
  (void)in_sizes; (void)n_in; (void)out_size; (void)ws_size;
  const float* word   = (const float*)d_in[0];
  const float* init_h = (const float*)d_in[1];
  const float* init_c = (const float*)d_in[2];
  const float* Wx     = (const float*)d_in[3];
  const float* Wh     = (const float*)d_in[4];
  const float* Wi     = (const float*)d_in[5];
  const float* Wdm    = (const float*)d_in[6];
  const float* Wsm    = (const float*)d_in[7];
  const float* bias   = (const float*)d_in[8];
  const float* gW     = (const float*)d_in[9];
  const float* gb     = (const float*)d_in[10];
  const int*   pos    = (const int*)d_in[11];
  const int*   mask   = (const int*)d_in[12];

  float* ws = (float*)d_ws;
  size_t off = 0;
  auto alloc = [&](size_t nel) { float* p = ws + off; off += nel; return p; };
  float* cA   = alloc(NHe);
  float* cB   = alloc(NHe);
  float* hS   = alloc(NHe);           // single h buffer; G aliases it (disjoint lifetimes)
  float* G    = hS;
  _Float16* Ahat = (_Float16*)alloc(5 * NHe / 2);          // 5 terms fp16, 84 MB
  _Float16* Bhat = (_Float16*)alloc(5 * 8 * 512 * 512 / 2); // 21 MB
  _Float16* Ghat = (_Float16*)alloc(512 * 512 / 2);         // 0.5 MB
  float* part = alloc(16 * Bn * Hn);
  float* np_  = alloc(8 * Bn * Hn);
  float* dp_  = alloc(8 * Bn * Hn);
  float* dh   = alloc(Bn * Hn);
  float* dc   = alloc(Bn * Hn);
  float* dh2  = alloc(Bn * Hn);
  float* dc2  = alloc(Bn * Hn);
  float* comb = alloc(Bn * Hn);
  float* gd   = alloc(Bn * Hn);
  float* go   = alloc(Bn * Hn);
  float* gfA  = alloc(Bn * Hn);
  float* dWd  = alloc(8 * Bn * Hn);
  // total ~ 209 MB

  dim3 blk(256);
  int g4 = (int)(NHe / 4 / 256);          // 8192 blocks
  int gbh = (Bn * Hn) / 256;              // 64 blocks

  k_convw<<<dim3(16, 16, 40), dim3(64), 0, stream>>>(Wx, Wh, Wsm, Wi, Bhat);
  k_convG<<<dim3(16, 4), blk, 0, stream>>>(gW, Ghat);
  k_prepW<<<dim3(128, 16), blk, 0, stream>>>(word, mask, Ahat);
  k_init<<<g4, blk, 0, stream>>>(init_h, init_c, mask, hS, cA);
  k_mean2<<<gbh, blk, 0, stream>>>(hS, cA, dh, dc);

  float* ccur = cA; float* cnxt = cB;
  for (int l = 0; l < NLAYER; ++l) {
    // NOTE: prepA + mean1a must consume hS BEFORE k_gemm1 overwrites it (G aliases hS)
    k_prepA<<<dim3(128, 16, 4), blk, 0, stream>>>(hS, pos, Ahat);
    k_mean1a<<<dim3(Bn, 8), blk, 0, stream>>>(hS, part);
    k_mean1b<<<16, blk, 0, stream>>>(part, comb);
    k_gates_small<<<gbh, blk, 0, stream>>>(dh, comb, gW, gb, gd, go, gfA);
    k_dWd<<<(8 * Bn * Hn) / 256, blk, 0, stream>>>(dh, Wdm, dWd);
    k_gemm1<<<dim3(128, 4), blk, 0, stream>>>(Ahat, Ghat, G);
    k_dummy1<<<dim3(Bn, 8), dim3(512), 0, stream>>>(G, gfA, ccur, mask, np_, dp_);
    k_dummy2<<<gbh, blk, 0, stream>>>(np_, dp_, gd, go, dc, dh2, dc2);

    float* hout = (l == NLAYER - 1) ? (float*)d_out : hS;
    k_mega<<<dim3(2048), blk, 0, stream>>>(
        ccur, Ahat, Bhat, pos, mask, dc, dWd, bias, hout, cnxt);

    float* t1;
    t1 = ccur; ccur = cnxt; cnxt = t1;
    t1 = dh; dh = dh2; dh2 = t1;
    t1 = dc; dc = dc2; dc2 = t1;
  }
}

// Round 3
// 2392.834 us; speedup vs baseline: 1.9190x; 1.0147x over previous
//
#include <hip/hip_runtime.h>
#include <cstddef>

#define Bn 32
#define Sn 512
#define Hn 512
#define Rn (Bn*Sn)
#define NLAYER 4
constexpr size_t NHe = (size_t)Rn * Hn;   // 8,388,608 elements per (B,S,H) tensor

typedef __attribute__((ext_vector_type(8))) _Float16 f16x8;
typedef __attribute__((ext_vector_type(4))) float f32x4;

__device__ __forceinline__ float sigf(float x) { return 1.f / (1.f + __expf(-x)); }
// 16B global -> LDS DMA (lane-linear dest; LDS base is wave-uniform + lane*16)
__device__ __forceinline__ void gl_lds16(const void* g, void* l) {
  __builtin_amdgcn_global_load_lds((const __attribute__((address_space(1))) void*)g,
                                   (__attribute__((address_space(3))) void*)l, 16, 0, 0);
}

// ---------------- init: h = init_h*m, c = init_c*m ----------------
__global__ void k_init(const float* __restrict__ ih, const float* __restrict__ ic,
                       const int* __restrict__ mask,
                       float* __restrict__ h, float* __restrict__ c) {
  size_t i = (size_t)blockIdx.x * blockDim.x + threadIdx.x;  // over NHe/4
  size_t n = i >> 7;
  float m = (float)mask[n];
  float4 b = ((const float4*)ih)[i];
  float4 d = ((const float4*)ic)[i];
  b.x *= m; b.y *= m; b.z *= m; b.w *= m;
  d.x *= m; d.y *= m; d.z *= m; d.w *= m;
  ((float4*)h)[i] = b; ((float4*)c)[i] = d;
}

// ---------------- mean2 (once): dh, dc ----------------
__global__ void k_mean2(const float* __restrict__ x, const float* __restrict__ y,
                        float* __restrict__ ox, float* __restrict__ oy) {
  int idx = blockIdx.x * blockDim.x + threadIdx.x;
  int b = idx >> 9, k = idx & 511;
  const float* px = x + (size_t)b * Sn * Hn + k;
  const float* py = y + (size_t)b * Sn * Hn + k;
  float sx = 0.f, sy = 0.f;
#pragma unroll 8
  for (int t = 0; t < Sn; ++t) { sx += px[(size_t)t * Hn]; sy += py[(size_t)t * Hn]; }
  ox[idx] = sx * (1.f / Sn); oy[idx] = sy * (1.f / Sn);
}

// ---------------- mean over s: two-stage, float4 ----------------
__global__ void k_mean1a(const float* __restrict__ x, float* __restrict__ part) {
  int b = blockIdx.x, sc = blockIdx.y;          // 32 x 8
  int k4 = threadIdx.x & 127;                   // float4 over 512 k
  int so = threadIdx.x >> 7;                    // 0/1
  const float4* px = (const float4*)x + ((size_t)(b * Sn + sc * 64 + so)) * 128 + k4;
  float4 s = make_float4(0.f, 0.f, 0.f, 0.f);
#pragma unroll 4
  for (int t = 0; t < 32; ++t) {
    float4 v = px[(size_t)t * 256];
    s.x += v.x; s.y += v.y; s.z += v.z; s.w += v.w;
  }
  ((float4*)part)[((size_t)(sc * 2 + so) * Bn + b) * 128 + k4] = s;
}
__global__ void k_mean1b(const float* __restrict__ part, float* __restrict__ comb) {
  int idx = blockIdx.x * blockDim.x + threadIdx.x;   // B*H/4 = 4096
  int b = idx >> 7, k4 = idx & 127;
  float4 s = make_float4(0.f, 0.f, 0.f, 0.f);
#pragma unroll
  for (int p = 0; p < 16; ++p) {
    float4 v = ((const float4*)part)[((size_t)p * Bn + b) * 128 + k4];
    s.x += v.x; s.y += v.y; s.z += v.z; s.w += v.w;
  }
  s.x *= (1.f / Sn); s.y *= (1.f / Sn); s.z *= (1.f / Sn); s.w *= (1.f / Sn);
  ((float4*)comb)[idx] = s;
}

// ---------------- small gates: gd, go, gfA ----------------
__global__ void k_gates_small(const float* __restrict__ dh, const float* __restrict__ comb,
                              const float* __restrict__ gW, const float* __restrict__ gb,
                              float* __restrict__ gd, float* __restrict__ go,
                              float* __restrict__ gfA) {
  int idx = blockIdx.x * blockDim.x + threadIdx.x;  // B*H
  int b = idx >> 9, k = idx & 511;
  const float* gW0 = gW;
  const float* gW1 = gW + 1 * Hn * Hn;
  const float* gW2 = gW + 2 * Hn * Hn;
  const float* gW3 = gW + 3 * Hn * Hn;
  const float* gW4 = gW + 4 * Hn * Hn;
  const float* dhb = dh + b * Hn;
  const float* cbp = comb + b * Hn;
  float s0 = 0.f, s1 = 0.f, s2 = 0.f, s3 = 0.f, s4 = 0.f;
#pragma unroll 4
  for (int j = 0; j < Hn; ++j) {
    float a = dhb[j], c2 = cbp[j];
    s0 += a * gW0[j * Hn + k];
    s1 += c2 * gW1[j * Hn + k];
    s2 += a * gW2[j * Hn + k];
    s3 += c2 * gW3[j * Hn + k];
    s4 += a * gW4[j * Hn + k];
  }
  gd[idx] = sigf(s0 + s1 + gb[k]);
  go[idx] = sigf(s2 + s3 + gb[Hn + k]);
  gfA[idx] = s4 + gb[2 * Hn + k];
}

// ---------------- dWd[g,b,k] = dummy_h[b,:] @ Wd[g,:,k] ----------------
__global__ void k_dWd(const float* __restrict__ dh, const float* __restrict__ Wd,
                      float* __restrict__ dWd) {
  int idx = blockIdx.x * blockDim.x + threadIdx.x;  // 8*B*H
  int k = idx & 511; int bg = idx >> 9; int b = bg & 31; int g = bg >> 5;
  const float* w = Wd + (size_t)g * Hn * Hn;
  const float* dhb = dh + b * Hn;
  float s = 0.f;
#pragma unroll 4
  for (int j = 0; j < Hn; ++j) s += dhb[j] * w[j * Hn + k];
  dWd[idx] = s;
}

// ---------------- dummy softmax: two-stage streamed ----------------
__global__ void k_dummy1(const float* __restrict__ G, const float* __restrict__ gfA,
                         const float* __restrict__ c, const int* __restrict__ mask,
                         float* __restrict__ np_, float* __restrict__ dp_) {
  int b = blockIdx.x, sc = blockIdx.y;   // 32 x 8, 512 threads
  int k = threadIdx.x;
  float gfa = gfA[(b << 9) | k];
  const float* Gp = G + ((size_t)(b * Sn + sc * 64)) * Hn + k;
  const float* cp = c + ((size_t)(b * Sn + sc * 64)) * Hn + k;
  const int* mp = mask + b * Sn + sc * 64;
  float num = 0.f, den = 0.f;
#pragma unroll 4
  for (int s = 0; s < 64; ++s) {
    float e = __expf(sigf(Gp[(size_t)s * Hn] + gfa));
    e = mp[s] ? e : 0.f;
    num += e * cp[(size_t)s * Hn];
    den += e;
  }
  np_[((size_t)sc * Bn + b) * Hn + k] = num;
  dp_[((size_t)sc * Bn + b) * Hn + k] = den;
}
__global__ void k_dummy2(const float* __restrict__ np_, const float* __restrict__ dp_,
                         const float* __restrict__ gd, const float* __restrict__ go,
                         const float* __restrict__ dc,
                         float* __restrict__ dh2, float* __restrict__ dc2) {
  int idx = blockIdx.x * blockDim.x + threadIdx.x;  // B*H
  int b = idx >> 9, k = idx & 511;
  float ed = __expf(gd[idx]);
  float num = ed * dc[idx], den = ed;
#pragma unroll
  for (int sc = 0; sc < 8; ++sc) {
    num += np_[((size_t)sc * Bn + b) * Hn + k];
    den += dp_[((size_t)sc * Bn + b) * Hn + k];
  }
  float d = num / den;
  dc2[idx] = d;
  dh2[idx] = go[idx] * tanhf(d);
}

// ---------------- weight pre-swizzle: f32 [g][k][n] -> fp16 frag-order superblocks ----------------
// Bhat superblock sb = (t*16 + nT)*16 + kcT, 8192 halfs (16KB) each.
// Interior: (((g*2 + ni)*4 + quad)*16 + l15)*8 + j ; element k=kcT*32+quad*8+j, n=nT*32+ni*16+l15
__global__ void k_convw(const float* __restrict__ Wx, const float* __restrict__ Wh,
                        const float* __restrict__ Wsm, const float* __restrict__ Wi,
                        _Float16* __restrict__ Bhat) {
  int kcT = blockIdx.x, nT = blockIdx.y, tg = blockIdx.z;  // 16,16,40
  int t = tg >> 3, g = tg & 7;
  const float* base;
  if (t == 0)      base = Wx  + (size_t)g * 262144;
  else if (t == 1) base = Wh  + (size_t)g * 524288;
  else if (t == 2) base = Wh  + (size_t)g * 524288 + 262144;
  else if (t == 3) base = Wsm + (size_t)g * 262144;
  else             base = Wi  + (size_t)g * 262144;
  size_t sbase = ((size_t)(t * 16 + nT) * 16 + kcT) * 8192 + (size_t)g * 1024;
  int lane = threadIdx.x;  // 64 threads
  for (int cch = lane; cch < 128; cch += 64) {
    int ni = cch >> 6, quad = (cch >> 4) & 3, l15 = cch & 15;
    int n = nT * 32 + ni * 16 + l15;
    int k0 = kcT * 32 + quad * 8;
    f16x8 w8;
#pragma unroll
    for (int j = 0; j < 8; ++j) w8[j] = (_Float16)base[(size_t)(k0 + j) * Hn + n];
    *(f16x8*)&Bhat[sbase + (size_t)cch * 8] = w8;
  }
}

// ---------------- gWhf pre-swizzle (once): superblock (nT4*16+kcT), 4096 halfs ----------------
// Interior: ((nj*4 + quad)*16 + l15)*8 + j ; element k=kcT*32+quad*8+j, n=nT4*128+nj*16+l15
__global__ void k_convG(const float* __restrict__ gW, _Float16* __restrict__ Ghat) {
  int kcT = blockIdx.x, nT4 = blockIdx.y;  // 16, 4
  int tid = threadIdx.x;                   // 256
  const float* w = gW + (size_t)5 * Hn * Hn;
  size_t sb = ((size_t)(nT4 * 16 + kcT)) * 4096;
#pragma unroll
  for (int half = 0; half < 2; ++half) {
    int st = half * 256 + tid;             // slot 0..511
    int nj = st >> 6, quad = (st >> 4) & 3, l15 = st & 15;
    int n = nT4 * 128 + nj * 16 + l15;
    int k0 = kcT * 32 + quad * 8;
    f16x8 w8;
#pragma unroll
    for (int j = 0; j < 8; ++j) w8[j] = (_Float16)w[(size_t)(k0 + j) * Hn + n];
    *(f16x8*)&Ghat[sb + (size_t)st * 8] = w8;
  }
}

// ---------------- A pre-convert per layer: terms 0..3 -> fp16 frag-order superblocks ----------------
// Ahat superblock sb = (t*128 + mb)*16 + kcT, 4096 halfs (8KB).
// Interior slot st = (rg*4 + quad)*16 + l15 ; element row=mb*128+rg*16+l15, k=kcT*32+quad*8+j
__global__ void k_prepA(const float* __restrict__ h, const int* __restrict__ pos,
                        _Float16* __restrict__ Ahat) {
  const int mb = blockIdx.x, kcT = blockIdx.y, t = blockIdx.z;  // 128,16,4
  const int tid = threadIdx.x;  // 256
  size_t sb = ((size_t)(t * 128 + mb) * 16 + kcT) * 4096;
#pragma unroll
  for (int half = 0; half < 2; ++half) {
    int st = half * 256 + tid;
    int rg = st >> 6, quad = (st >> 4) & 3, l15 = st & 15;
    int r = mb * 128 + rg * 16 + l15;
    int srow = r & (Sn - 1);
    int k0 = kcT * 32 + quad * 8;
    const float* base = h + (size_t)r * Hn + k0;
    float v[8];
    if (t == 0) {
#pragma unroll
      for (int j = 0; j < 8; ++j) v[j] = base[j];
    } else if (t == 1) {
#pragma unroll
      for (int j = 0; j < 8; ++j) v[j] = 0.f;
      if (srow >= 1) { const float* p = base - Hn;
#pragma unroll
        for (int j = 0; j < 8; ++j) v[j] += p[j]; }
      if (srow >= 2) { const float* p = base - 2 * Hn;
#pragma unroll
        for (int j = 0; j < 8; ++j) v[j] += p[j]; }
    } else if (t == 2) {
#pragma unroll
      for (int j = 0; j < 8; ++j) v[j] = 0.f;
      if (srow <= Sn - 2) { const float* p = base + Hn;
#pragma unroll
        for (int j = 0; j < 8; ++j) v[j] += p[j]; }
      if (srow <= Sn - 3) { const float* p = base + 2 * Hn;
#pragma unroll
        for (int j = 0; j < 8; ++j) v[j] += p[j]; }
    } else {
      int pp = pos[r];
      if (pp) {
        const float* p = h + ((size_t)((r >> 9) * Sn + pp - 1)) * Hn + k0;
#pragma unroll
        for (int j = 0; j < 8; ++j) v[j] = p[j];
      } else {
#pragma unroll
        for (int j = 0; j < 8; ++j) v[j] = 0.f;
      }
    }
    f16x8 o8;
#pragma unroll
    for (int j = 0; j < 8; ++j) o8[j] = (_Float16)v[j];
    *(f16x8*)&Ahat[sb + (size_t)st * 8] = o8;
  }
}

// word term (t=4): layer-invariant, run once
__global__ void k_prepW(const float* __restrict__ w, const int* __restrict__ mask,
                        _Float16* __restrict__ Ahat) {
  const int mb = blockIdx.x, kcT = blockIdx.y;  // 128,16
  const int tid = threadIdx.x;
  size_t sb = ((size_t)(4 * 128 + mb) * 16 + kcT) * 4096;
#pragma unroll
  for (int half = 0; half < 2; ++half) {
    int st = half * 256 + tid;
    int rg = st >> 6, quad = (st >> 4) & 3, l15 = st & 15;
    int r = mb * 128 + rg * 16 + l15;
    int k0 = kcT * 32 + quad * 8;
    float mf = (float)mask[r];
    const float* base = w + (size_t)r * Hn + k0;
    f16x8 o8;
#pragma unroll
    for (int j = 0; j < 8; ++j) o8[j] = (_Float16)(base[j] * mf);
    *(f16x8*)&Ahat[sb + (size_t)st * 8] = o8;
  }
}

// ---------------- G = h @ gWhf (fp16 MFMA, reuses Ahat term 0) ----------------
// BM=128, BN=128, grid (128 mb, 4 nT4), 256 threads = 4 waves; wave owns 32 rows.
__global__ __launch_bounds__(256, 3) void k_gemm1(const _Float16* __restrict__ Ahat,
                                                  const _Float16* __restrict__ Ghat,
                                                  float* __restrict__ G) {
  __shared__ _Float16 As[2][4096];
  __shared__ _Float16 Bs[2][4096];
  const int tid = threadIdx.x;
  const int mb = blockIdx.x, nT4 = blockIdx.y;
  const int lane = tid & 63, wid = tid >> 6;
  const int quad = lane >> 4, l15 = lane & 15;
  const int afo0 = (((wid * 2 + 0) * 4 + quad) * 16 + l15) * 8;
  const int afo1 = (((wid * 2 + 1) * 4 + quad) * 16 + l15) * 8;

  f32x4 acc[2][8];
#pragma unroll
  for (int mi = 0; mi < 2; ++mi)
#pragma unroll
    for (int nj = 0; nj < 8; ++nj) acc[mi][nj] = (f32x4){0.f, 0.f, 0.f, 0.f};

  auto stage = [&](int buf, int kcT) {
    const int4* sa = (const int4*)Ahat + ((size_t)(mb * 16 + kcT) << 9);
    const int4* sbp = (const int4*)Ghat + ((size_t)(nT4 * 16 + kcT) << 9);
#pragma unroll
    for (int q = 0; q < 2; ++q) {
      gl_lds16(sa + q * 256 + tid, &As[buf][(q * 256 + tid) * 8]);
      gl_lds16(sbp + q * 256 + tid, &Bs[buf][(q * 256 + tid) * 8]);
    }
  };

  stage(0, 0);
  __syncthreads();
#pragma unroll 1
  for (int kcT = 0; kcT < 16; ++kcT) {
    const int cur = kcT & 1;
    if (kcT < 15) stage(cur ^ 1, kcT + 1);
    f16x8 a0 = *(const f16x8*)&As[cur][afo0];
    f16x8 a1 = *(const f16x8*)&As[cur][afo1];
#pragma unroll
    for (int nj = 0; nj < 8; ++nj) {
      f16x8 bh = *(const f16x8*)&Bs[cur][((nj * 4 + quad) * 16 + l15) * 8];
      acc[0][nj] = __builtin_amdgcn_mfma_f32_16x16x32_f16(a0, bh, acc[0][nj], 0, 0, 0);
      acc[1][nj] = __builtin_amdgcn_mfma_f32_16x16x32_f16(a1, bh, acc[1][nj], 0, 0, 0);
    }
    __syncthreads();
  }
#pragma unroll
  for (int mi = 0; mi < 2; ++mi)
#pragma unroll
    for (int r = 0; r < 4; ++r) {
      int row = mb * 128 + wid * 32 + mi * 16 + quad * 4 + r;
      float* gp = G + (size_t)row * Hn + nT4 * 128 + l15;
#pragma unroll
      for (int nj = 0; nj < 8; ++nj) gp[nj * 16] = acc[mi][nj][r];
    }
}

// ---------------- mega GEMM: all 8 groups, 5 terms, fused gate epilogue ----------------
// BM=128, BN=32 (x8 groups), BK=32. Wave = 64 rows x 16 cols x all 8 groups
// (4 A-frags + 8 B-frags = 12 ds_read_b128/wave/chunk, down from 18).
// Depth-2 pipeline: 3 LDS buffers, raw s_barrier + counted s_waitcnt vmcnt(6)
// (T3/T4) so staged loads span two compute phases. setprio around MFMA cluster (T5).
__global__ __launch_bounds__(256, 2) void k_mega(
    const float* __restrict__ c,
    const _Float16* __restrict__ Ahat, const _Float16* __restrict__ Bhat,
    const int* __restrict__ pos, const int* __restrict__ mask,
    const float* __restrict__ dc, const float* __restrict__ dWd,
    const float* __restrict__ bias,
    float* __restrict__ hout, float* __restrict__ cout) {
  __shared__ _Float16 As[3][4096];   // 8KB per buffer
  __shared__ _Float16 Bs[3][8192];   // 16KB per buffer

  const int tid = threadIdx.x;
  const int id = blockIdx.x;          // 2048
  const int loc = id >> 3;            // 0..255
  const int mb = loc >> 1;            // same-mb pair adjacent -> A superblocks L2-shared
  const int nT = (id & 7) * 2 + (loc & 1);
  const int m0 = mb * 128;
  const int n0 = nT * 32;
  const int bb = m0 >> 9;             // batch index (tile spans one batch)

  const int lane = tid & 63, wid = tid >> 6;
  const int quad = lane >> 4, l15 = lane & 15;
  const int row_half = wid >> 1;      // wave covers rows [row_half*64, +64)
  const int col_half = wid & 1;       // wave covers cols [col_half*16, +16)

  // A-frag LDS offsets (halfs), rg = row_half*4 + mi
  int afo[4];
#pragma unroll
  for (int mi = 0; mi < 4; ++mi)
    afo[mi] = (((row_half * 4 + mi) * 4 + quad) * 16 + l15) * 8;
  // B-frag LDS offsets per g: ((g*2 + col_half)*4 + quad)*16 + l15)*8
  const int bfo_base = ((col_half * 4 + quad) * 16 + l15) * 8;   // + g*1024

  f32x4 acc[8][4];
#pragma unroll
  for (int g = 0; g < 8; ++g)
#pragma unroll
    for (int mi = 0; mi < 4; ++mi) acc[g][mi] = (f32x4){0.f, 0.f, 0.f, 0.f};

  auto stage = [&](int buf, int cn) {
    const int t = cn >> 4, kcT = cn & 15;
    const int4* sa = (const int4*)Ahat + ((size_t)((t * 128 + mb) * 16 + kcT) << 9);
    const int4* sbp = (const int4*)Bhat + ((size_t)((t * 16 + nT) * 16 + kcT) << 10);
#pragma unroll
    for (int q = 0; q < 2; ++q)
      gl_lds16(sa + q * 256 + tid, &As[buf][(q * 256 + tid) * 8]);
#pragma unroll
    for (int q = 0; q < 4; ++q)
      gl_lds16(sbp + q * 256 + tid, &Bs[buf][(q * 256 + tid) * 8]);
  };
  // 6 global_load_lds per thread per stage -> vmcnt counts 6 per stage.

  stage(0, 0);
  stage(1, 1);
  int cur = 0;
#pragma unroll 1
  for (int ci = 0; ci < 80; ++ci) {
    // Invariant at top: outstanding = buf[ci] (6) + buf[ci+1] (6, if ci<79).
    if (ci < 79) asm volatile("s_waitcnt vmcnt(6)" ::: "memory");
    else         asm volatile("s_waitcnt vmcnt(0)" ::: "memory");
    __builtin_amdgcn_s_barrier();     // all waves: buf[ci] ready; buf[ci-1] reads retired
    if (ci + 2 < 80) {
      int b2 = cur + 2; if (b2 >= 3) b2 -= 3;   // == buf[ci-1], safe to overwrite
      stage(b2, ci + 2);
    }
    f16x8 a0 = *(const f16x8*)&As[cur][afo[0]];
    f16x8 a1 = *(const f16x8*)&As[cur][afo[1]];
    f16x8 a2 = *(const f16x8*)&As[cur][afo[2]];
    f16x8 a3 = *(const f16x8*)&As[cur][afo[3]];
    __builtin_amdgcn_s_setprio(1);
#pragma unroll
    for (int g = 0; g < 8; ++g) {
      f16x8 bh = *(const f16x8*)&Bs[cur][bfo_base + g * 1024];
      acc[g][0] = __builtin_amdgcn_mfma_f32_16x16x32_f16(a0, bh, acc[g][0], 0, 0, 0);
      acc[g][1] = __builtin_amdgcn_mfma_f32_16x16x32_f16(a1, bh, acc[g][1], 0, 0, 0);
      acc[g][2] = __builtin_amdgcn_mfma_f32_16x16x32_f16(a2, bh, acc[g][2], 0, 0, 0);
      acc[g][3] = __builtin_amdgcn_mfma_f32_16x16x32_f16(a3, bh, acc[g][3], 0, 0, 0);
    }
    __builtin_amdgcn_s_setprio(0);
    cur = (cur == 2) ? 0 : cur + 1;
  }

  // ---- fused epilogue (per thread: 16 rows x 1 col) ----
  const int col = n0 + col_half * 16 + l15;
  const float tdcv = dc[bb * Hn + col];
  float biasr[8], dwdr[8];
#pragma unroll
  for (int g = 0; g < 8; ++g) {
    biasr[g] = bias[g * Hn + col];
    dwdr[g] = dWd[((size_t)g * Bn + bb) * Hn + col];
  }

#pragma unroll
  for (int mi = 0; mi < 4; ++mi) {
#pragma unroll
    for (int r = 0; r < 4; ++r) {
      const int row = m0 + row_half * 64 + mi * 16 + quad * 4 + r;
      const int srow = row & (Sn - 1);
      const float mf = (float)mask[row];
      const int pp = pos[row];
      const size_t rb = (size_t)row * Hn;
      float cf = c[rb + col];
      float cb = 0.f, ca = 0.f;
      if (srow >= 1) cb = c[rb - Hn + col];
      if (srow >= 2) cb += c[rb - 2 * Hn + col];
      if (srow <= Sn - 2) ca = c[rb + Hn + col];
      if (srow <= Sn - 3) ca += c[rb + 2 * Hn + col];
      float sw = pp ? c[((size_t)(bb * Sn + pp - 1)) * Hn + col] : 0.f;
      float z[8];
#pragma unroll
      for (int g = 0; g < 8; ++g)
        z[g] = acc[g][mi][r] + biasr[g] + dwdr[g];
      float e0 = __expf(sigf(z[0]));
      float e1 = __expf(sigf(z[1]));
      float e2 = __expf(sigf(z[2]));
      float e3 = __expf(sigf(z[3]));
      float e4 = __expf(sigf(z[4]));
      float e5 = __expf(sigf(z[5]));
      float inv = 1.f / (e0 + e1 + e2 + e3 + e4 + e5);
      float o = sigf(z[6]);
      float u = tanhf(z[7]);
      float cn = inv * (e0 * cb + e1 * ca + e2 * cf + e3 * tdcv + e4 * sw + e5 * u);
      cout[rb + col] = cn * mf;
      hout[rb + col] = o * tanhf(cn) * mf;
    }
  }
}

extern "C" void kernel_launch(void* const* d_in, const int* in_sizes, int n_in,
                              void* d_out, int out_size, void* d_ws, size_t ws_size,
                              hipStream_t stream) {
  (void)in_sizes; (void)n_in; (void)out_size; (void)ws_size;
  const float* word   = (const float*)d_in[0];
  const float* init_h = (const float*)d_in[1];
  const float* init_c = (const float*)d_in[2];
  const float* Wx     = (const float*)d_in[3];
  const float* Wh     = (const float*)d_in[4];
  const float* Wi     = (const float*)d_in[5];
  const float* Wdm    = (const float*)d_in[6];
  const float* Wsm    = (const float*)d_in[7];
  const float* bias   = (const float*)d_in[8];
  const float* gW     = (const float*)d_in[9];
  const float* gb     = (const float*)d_in[10];
  const int*   pos    = (const int*)d_in[11];
  const int*   mask   = (const int*)d_in[12];

  float* ws = (float*)d_ws;
  size_t off = 0;
  auto alloc = [&](size_t nel) { float* p = ws + off; off += nel; return p; };
  float* cA   = alloc(NHe);
  float* cB   = alloc(NHe);
  float* hS   = alloc(NHe);           // single h buffer; G aliases it (disjoint lifetimes)
  float* G    = hS;
  _Float16* Ahat = (_Float16*)alloc(5 * NHe / 2);          // 5 terms fp16, 84 MB
  _Float16* Bhat = (_Float16*)alloc(5 * 8 * 512 * 512 / 2); // 21 MB
  _Float16* Ghat = (_Float16*)alloc(512 * 512 / 2);         // 0.5 MB
  float* part = alloc(16 * Bn * Hn);
  float* np_  = alloc(8 * Bn * Hn);
  float* dp_  = alloc(8 * Bn * Hn);
  float* dh   = alloc(Bn * Hn);
  float* dc   = alloc(Bn * Hn);
  float* dh2  = alloc(Bn * Hn);
  float* dc2  = alloc(Bn * Hn);
  float* comb = alloc(Bn * Hn);
  float* gd   = alloc(Bn * Hn);
  float* go   = alloc(Bn * Hn);
  float* gfA  = alloc(Bn * Hn);
  float* dWd  = alloc(8 * Bn * Hn);
  // total ~ 209 MB

  dim3 blk(256);
  int g4 = (int)(NHe / 4 / 256);          // 8192 blocks
  int gbh = (Bn * Hn) / 256;              // 64 blocks

  k_convw<<<dim3(16, 16, 40), dim3(64), 0, stream>>>(Wx, Wh, Wsm, Wi, Bhat);
  k_convG<<<dim3(16, 4), blk, 0, stream>>>(gW, Ghat);
  k_prepW<<<dim3(128, 16), blk, 0, stream>>>(word, mask, Ahat);
  k_init<<<g4, blk, 0, stream>>>(init_h, init_c, mask, hS, cA);
  k_mean2<<<gbh, blk, 0, stream>>>(hS, cA, dh, dc);

  float* ccur = cA; float* cnxt = cB;
  for (int l = 0; l < NLAYER; ++l) {
    // NOTE: prepA + mean1a must consume hS BEFORE k_gemm1 overwrites it (G aliases hS)
    k_prepA<<<dim3(128, 16, 4), blk, 0, stream>>>(hS, pos, Ahat);
    k_mean1a<<<dim3(Bn, 8), blk, 0, stream>>>(hS, part);
    k_mean1b<<<16, blk, 0, stream>>>(part, comb);
    k_gates_small<<<gbh, blk, 0, stream>>>(dh, comb, gW, gb, gd, go, gfA);
    k_dWd<<<(8 * Bn * Hn) / 256, blk, 0, stream>>>(dh, Wdm, dWd);
    k_gemm1<<<dim3(128, 4), blk, 0, stream>>>(Ahat, Ghat, G);
    k_dummy1<<<dim3(Bn, 8), dim3(512), 0, stream>>>(G, gfA, ccur, mask, np_, dp_);
    k_dummy2<<<gbh, blk, 0, stream>>>(np_, dp_, gd, go, dc, dh2, dc2);

    float* hout = (l == NLAYER - 1) ? (float*)d_out : hS;
    k_mega<<<dim3(2048), blk, 0, stream>>>(
        ccur, Ahat, Bhat, pos, mask, dc, dWd, bias, hout, cnxt);

    float* t1;
    t1 = ccur; ccur = cnxt; cnxt = t1;
    t1 = dh; dh = dh2; dh2 = t1;
    t1 = dc; dc = dc2; dc2 = t1;
  }
}

// Round 4
// 2276.094 us; speedup vs baseline: 2.0175x; 1.0513x over previous
//
#include <hip/hip_runtime.h>
#include <cstddef>

#define Bn 32
#define Sn 512
#define Hn 512
#define Rn (Bn*Sn)
#define NLAYER 4
constexpr size_t NHe = (size_t)Rn * Hn;   // 8,388,608 elements per (B,S,H) tensor

typedef __attribute__((ext_vector_type(8))) _Float16 f16x8;
typedef __attribute__((ext_vector_type(4))) float f32x4;

__device__ __forceinline__ float sigf(float x) { return 1.f / (1.f + __expf(-x)); }
// 16B global -> LDS DMA (lane-linear dest; LDS base is wave-uniform + lane*16)
__device__ __forceinline__ void gl_lds16(const void* g, void* l) {
  __builtin_amdgcn_global_load_lds((const __attribute__((address_space(1))) void*)g,
                                   (__attribute__((address_space(3))) void*)l, 16, 0, 0);
}
#define VMCNT(n) asm volatile("s_waitcnt vmcnt(" #n ")" ::: "memory")

// ---------------- init: h = init_h*m, c = init_c*m ----------------
__global__ void k_init(const float* __restrict__ ih, const float* __restrict__ ic,
                       const int* __restrict__ mask,
                       float* __restrict__ h, float* __restrict__ c) {
  size_t i = (size_t)blockIdx.x * blockDim.x + threadIdx.x;  // over NHe/4
  size_t n = i >> 7;
  float m = (float)mask[n];
  float4 b = ((const float4*)ih)[i];
  float4 d = ((const float4*)ic)[i];
  b.x *= m; b.y *= m; b.z *= m; b.w *= m;
  d.x *= m; d.y *= m; d.z *= m; d.w *= m;
  ((float4*)h)[i] = b; ((float4*)c)[i] = d;
}

// ---------------- mean2 (once): dh, dc ----------------
__global__ void k_mean2(const float* __restrict__ x, const float* __restrict__ y,
                        float* __restrict__ ox, float* __restrict__ oy) {
  int idx = blockIdx.x * blockDim.x + threadIdx.x;
  int b = idx >> 9, k = idx & 511;
  const float* px = x + (size_t)b * Sn * Hn + k;
  const float* py = y + (size_t)b * Sn * Hn + k;
  float sx = 0.f, sy = 0.f;
#pragma unroll 8
  for (int t = 0; t < Sn; ++t) { sx += px[(size_t)t * Hn]; sy += py[(size_t)t * Hn]; }
  ox[idx] = sx * (1.f / Sn); oy[idx] = sy * (1.f / Sn);
}

// ---------------- mean over s: two-stage, float4 ----------------
__global__ void k_mean1a(const float* __restrict__ x, float* __restrict__ part) {
  int b = blockIdx.x, sc = blockIdx.y;          // 32 x 8
  int k4 = threadIdx.x & 127;                   // float4 over 512 k
  int so = threadIdx.x >> 7;                    // 0/1
  const float4* px = (const float4*)x + ((size_t)(b * Sn + sc * 64 + so)) * 128 + k4;
  float4 s = make_float4(0.f, 0.f, 0.f, 0.f);
#pragma unroll 4
  for (int t = 0; t < 32; ++t) {
    float4 v = px[(size_t)t * 256];
    s.x += v.x; s.y += v.y; s.z += v.z; s.w += v.w;
  }
  ((float4*)part)[((size_t)(sc * 2 + so) * Bn + b) * 128 + k4] = s;
}
__global__ void k_mean1b(const float* __restrict__ part, float* __restrict__ comb) {
  int idx = blockIdx.x * blockDim.x + threadIdx.x;   // B*H/4 = 4096
  int b = idx >> 7, k4 = idx & 127;
  float4 s = make_float4(0.f, 0.f, 0.f, 0.f);
#pragma unroll
  for (int p = 0; p < 16; ++p) {
    float4 v = ((const float4*)part)[((size_t)p * Bn + b) * 128 + k4];
    s.x += v.x; s.y += v.y; s.z += v.z; s.w += v.w;
  }
  s.x *= (1.f / Sn); s.y *= (1.f / Sn); s.z *= (1.f / Sn); s.w *= (1.f / Sn);
  ((float4*)comb)[idx] = s;
}

// ---------------- small gates: gd, go, gfA ----------------
__global__ void k_gates_small(const float* __restrict__ dh, const float* __restrict__ comb,
                              const float* __restrict__ gW, const float* __restrict__ gb,
                              float* __restrict__ gd, float* __restrict__ go,
                              float* __restrict__ gfA) {
  int idx = blockIdx.x * blockDim.x + threadIdx.x;  // B*H
  int b = idx >> 9, k = idx & 511;
  const float* gW0 = gW;
  const float* gW1 = gW + 1 * Hn * Hn;
  const float* gW2 = gW + 2 * Hn * Hn;
  const float* gW3 = gW + 3 * Hn * Hn;
  const float* gW4 = gW + 4 * Hn * Hn;
  const float* dhb = dh + b * Hn;
  const float* cbp = comb + b * Hn;
  float s0 = 0.f, s1 = 0.f, s2 = 0.f, s3 = 0.f, s4 = 0.f;
#pragma unroll 4
  for (int j = 0; j < Hn; ++j) {
    float a = dhb[j], c2 = cbp[j];
    s0 += a * gW0[j * Hn + k];
    s1 += c2 * gW1[j * Hn + k];
    s2 += a * gW2[j * Hn + k];
    s3 += c2 * gW3[j * Hn + k];
    s4 += a * gW4[j * Hn + k];
  }
  gd[idx] = sigf(s0 + s1 + gb[k]);
  go[idx] = sigf(s2 + s3 + gb[Hn + k]);
  gfA[idx] = s4 + gb[2 * Hn + k];
}

// ---------------- dWd[g,b,k] = dummy_h[b,:] @ Wd[g,:,k] ----------------
__global__ void k_dWd(const float* __restrict__ dh, const float* __restrict__ Wd,
                      float* __restrict__ dWd) {
  int idx = blockIdx.x * blockDim.x + threadIdx.x;  // 8*B*H
  int k = idx & 511; int bg = idx >> 9; int b = bg & 31; int g = bg >> 5;
  const float* w = Wd + (size_t)g * Hn * Hn;
  const float* dhb = dh + b * Hn;
  float s = 0.f;
#pragma unroll 4
  for (int j = 0; j < Hn; ++j) s += dhb[j] * w[j * Hn + k];
  dWd[idx] = s;
}

// ---------------- dummy softmax: two-stage streamed ----------------
__global__ void k_dummy1(const float* __restrict__ G, const float* __restrict__ gfA,
                         const float* __restrict__ c, const int* __restrict__ mask,
                         float* __restrict__ np_, float* __restrict__ dp_) {
  int b = blockIdx.x, sc = blockIdx.y;   // 32 x 8, 512 threads
  int k = threadIdx.x;
  float gfa = gfA[(b << 9) | k];
  const float* Gp = G + ((size_t)(b * Sn + sc * 64)) * Hn + k;
  const float* cp = c + ((size_t)(b * Sn + sc * 64)) * Hn + k;
  const int* mp = mask + b * Sn + sc * 64;
  float num = 0.f, den = 0.f;
#pragma unroll 4
  for (int s = 0; s < 64; ++s) {
    float e = __expf(sigf(Gp[(size_t)s * Hn] + gfa));
    e = mp[s] ? e : 0.f;
    num += e * cp[(size_t)s * Hn];
    den += e;
  }
  np_[((size_t)sc * Bn + b) * Hn + k] = num;
  dp_[((size_t)sc * Bn + b) * Hn + k] = den;
}
__global__ void k_dummy2(const float* __restrict__ np_, const float* __restrict__ dp_,
                         const float* __restrict__ gd, const float* __restrict__ go,
                         const float* __restrict__ dc,
                         float* __restrict__ dh2, float* __restrict__ dc2) {
  int idx = blockIdx.x * blockDim.x + threadIdx.x;  // B*H
  int b = idx >> 9, k = idx & 511;
  float ed = __expf(gd[idx]);
  float num = ed * dc[idx], den = ed;
#pragma unroll
  for (int sc = 0; sc < 8; ++sc) {
    num += np_[((size_t)sc * Bn + b) * Hn + k];
    den += dp_[((size_t)sc * Bn + b) * Hn + k];
  }
  float d = num / den;
  dc2[idx] = d;
  dh2[idx] = go[idx] * tanhf(d);
}

// ---------------- weight pre-swizzle: f32 [g][k][n] -> fp16 frag-order superblocks ----------------
// Bhat superblock sb = (t*16 + nT)*16 + kcT, 8192 halfs (16KB) each.
// Interior: (((g*2 + ni)*4 + quad)*16 + l15)*8 + j ; element k=kcT*32+quad*8+j, n=nT*32+ni*16+l15
__global__ void k_convw(const float* __restrict__ Wx, const float* __restrict__ Wh,
                        const float* __restrict__ Wsm, const float* __restrict__ Wi,
                        _Float16* __restrict__ Bhat) {
  int kcT = blockIdx.x, nT = blockIdx.y, tg = blockIdx.z;  // 16,16,40
  int t = tg >> 3, g = tg & 7;
  const float* base;
  if (t == 0)      base = Wx  + (size_t)g * 262144;
  else if (t == 1) base = Wh  + (size_t)g * 524288;
  else if (t == 2) base = Wh  + (size_t)g * 524288 + 262144;
  else if (t == 3) base = Wsm + (size_t)g * 262144;
  else             base = Wi  + (size_t)g * 262144;
  size_t sbase = ((size_t)(t * 16 + nT) * 16 + kcT) * 8192 + (size_t)g * 1024;
  int lane = threadIdx.x;  // 64 threads
  for (int cch = lane; cch < 128; cch += 64) {
    int ni = cch >> 6, quad = (cch >> 4) & 3, l15 = cch & 15;
    int n = nT * 32 + ni * 16 + l15;
    int k0 = kcT * 32 + quad * 8;
    f16x8 w8;
#pragma unroll
    for (int j = 0; j < 8; ++j) w8[j] = (_Float16)base[(size_t)(k0 + j) * Hn + n];
    *(f16x8*)&Bhat[sbase + (size_t)cch * 8] = w8;
  }
}

// ---------------- gWhf pre-swizzle (once): superblock (nT4*16+kcT), 4096 halfs ----------------
// Interior: ((nj*4 + quad)*16 + l15)*8 + j ; element k=kcT*32+quad*8+j, n=nT4*128+nj*16+l15
__global__ void k_convG(const float* __restrict__ gW, _Float16* __restrict__ Ghat) {
  int kcT = blockIdx.x, nT4 = blockIdx.y;  // 16, 4
  int tid = threadIdx.x;                   // 256
  const float* w = gW + (size_t)5 * Hn * Hn;
  size_t sb = ((size_t)(nT4 * 16 + kcT)) * 4096;
#pragma unroll
  for (int half = 0; half < 2; ++half) {
    int st = half * 256 + tid;             // slot 0..511
    int nj = st >> 6, quad = (st >> 4) & 3, l15 = st & 15;
    int n = nT4 * 128 + nj * 16 + l15;
    int k0 = kcT * 32 + quad * 8;
    f16x8 w8;
#pragma unroll
    for (int j = 0; j < 8; ++j) w8[j] = (_Float16)w[(size_t)(k0 + j) * Hn + n];
    *(f16x8*)&Ghat[sb + (size_t)st * 8] = w8;
  }
}

// ---------------- A pre-convert per layer: terms 0..3 -> fp16 frag-order superblocks ----------------
// Ahat superblock sb = (t*128 + mb)*16 + kcT, 4096 halfs (8KB).
// Interior slot st = (rg*4 + quad)*16 + l15 ; element row=mb*128+rg*16+l15, k=kcT*32+quad*8+j
__global__ void k_prepA(const float* __restrict__ h, const int* __restrict__ pos,
                        _Float16* __restrict__ Ahat) {
  const int mb = blockIdx.x, kcT = blockIdx.y, t = blockIdx.z;  // 128,16,4
  const int tid = threadIdx.x;  // 256
  size_t sb = ((size_t)(t * 128 + mb) * 16 + kcT) * 4096;
#pragma unroll
  for (int half = 0; half < 2; ++half) {
    int st = half * 256 + tid;
    int rg = st >> 6, quad = (st >> 4) & 3, l15 = st & 15;
    int r = mb * 128 + rg * 16 + l15;
    int srow = r & (Sn - 1);
    int k0 = kcT * 32 + quad * 8;
    const float* base = h + (size_t)r * Hn + k0;
    float v[8];
    if (t == 0) {
#pragma unroll
      for (int j = 0; j < 8; ++j) v[j] = base[j];
    } else if (t == 1) {
#pragma unroll
      for (int j = 0; j < 8; ++j) v[j] = 0.f;
      if (srow >= 1) { const float* p = base - Hn;
#pragma unroll
        for (int j = 0; j < 8; ++j) v[j] += p[j]; }
      if (srow >= 2) { const float* p = base - 2 * Hn;
#pragma unroll
        for (int j = 0; j < 8; ++j) v[j] += p[j]; }
    } else if (t == 2) {
#pragma unroll
      for (int j = 0; j < 8; ++j) v[j] = 0.f;
      if (srow <= Sn - 2) { const float* p = base + Hn;
#pragma unroll
        for (int j = 0; j < 8; ++j) v[j] += p[j]; }
      if (srow <= Sn - 3) { const float* p = base + 2 * Hn;
#pragma unroll
        for (int j = 0; j < 8; ++j) v[j] += p[j]; }
    } else {
      int pp = pos[r];
      if (pp) {
        const float* p = h + ((size_t)((r >> 9) * Sn + pp - 1)) * Hn + k0;
#pragma unroll
        for (int j = 0; j < 8; ++j) v[j] = p[j];
      } else {
#pragma unroll
        for (int j = 0; j < 8; ++j) v[j] = 0.f;
      }
    }
    f16x8 o8;
#pragma unroll
    for (int j = 0; j < 8; ++j) o8[j] = (_Float16)v[j];
    *(f16x8*)&Ahat[sb + (size_t)st * 8] = o8;
  }
}

// word term (t=4): layer-invariant, run once
__global__ void k_prepW(const float* __restrict__ w, const int* __restrict__ mask,
                        _Float16* __restrict__ Ahat) {
  const int mb = blockIdx.x, kcT = blockIdx.y;  // 128,16
  const int tid = threadIdx.x;
  size_t sb = ((size_t)(4 * 128 + mb) * 16 + kcT) * 4096;
#pragma unroll
  for (int half = 0; half < 2; ++half) {
    int st = half * 256 + tid;
    int rg = st >> 6, quad = (st >> 4) & 3, l15 = st & 15;
    int r = mb * 128 + rg * 16 + l15;
    int k0 = kcT * 32 + quad * 8;
    float mf = (float)mask[r];
    const float* base = w + (size_t)r * Hn + k0;
    f16x8 o8;
#pragma unroll
    for (int j = 0; j < 8; ++j) o8[j] = (_Float16)(base[j] * mf);
    *(f16x8*)&Ahat[sb + (size_t)st * 8] = o8;
  }
}

// ---------------- G = h @ gWhf (fp16 MFMA, reuses Ahat term 0) ----------------
__global__ __launch_bounds__(256, 3) void k_gemm1(const _Float16* __restrict__ Ahat,
                                                  const _Float16* __restrict__ Ghat,
                                                  float* __restrict__ G) {
  __shared__ _Float16 As[2][4096];
  __shared__ _Float16 Bs[2][4096];
  const int tid = threadIdx.x;
  const int mb = blockIdx.x, nT4 = blockIdx.y;
  const int lane = tid & 63, wid = tid >> 6;
  const int quad = lane >> 4, l15 = lane & 15;
  const int afo0 = (((wid * 2 + 0) * 4 + quad) * 16 + l15) * 8;
  const int afo1 = (((wid * 2 + 1) * 4 + quad) * 16 + l15) * 8;

  f32x4 acc[2][8];
#pragma unroll
  for (int mi = 0; mi < 2; ++mi)
#pragma unroll
    for (int nj = 0; nj < 8; ++nj) acc[mi][nj] = (f32x4){0.f, 0.f, 0.f, 0.f};

  auto stage = [&](int buf, int kcT) {
    const int4* sa = (const int4*)Ahat + ((size_t)(mb * 16 + kcT) << 9);
    const int4* sbp = (const int4*)Ghat + ((size_t)(nT4 * 16 + kcT) << 9);
#pragma unroll
    for (int q = 0; q < 2; ++q) {
      gl_lds16(sa + q * 256 + tid, &As[buf][(q * 256 + tid) * 8]);
      gl_lds16(sbp + q * 256 + tid, &Bs[buf][(q * 256 + tid) * 8]);
    }
  };

  stage(0, 0);
  __syncthreads();
#pragma unroll 1
  for (int kcT = 0; kcT < 16; ++kcT) {
    const int cur = kcT & 1;
    if (kcT < 15) stage(cur ^ 1, kcT + 1);
    f16x8 a0 = *(const f16x8*)&As[cur][afo0];
    f16x8 a1 = *(const f16x8*)&As[cur][afo1];
#pragma unroll
    for (int nj = 0; nj < 8; ++nj) {
      f16x8 bh = *(const f16x8*)&Bs[cur][((nj * 4 + quad) * 16 + l15) * 8];
      acc[0][nj] = __builtin_amdgcn_mfma_f32_16x16x32_f16(a0, bh, acc[0][nj], 0, 0, 0);
      acc[1][nj] = __builtin_amdgcn_mfma_f32_16x16x32_f16(a1, bh, acc[1][nj], 0, 0, 0);
    }
    __syncthreads();
  }
#pragma unroll
  for (int mi = 0; mi < 2; ++mi)
#pragma unroll
    for (int r = 0; r < 4; ++r) {
      int row = mb * 128 + wid * 32 + mi * 16 + quad * 4 + r;
      float* gp = G + (size_t)row * Hn + nT4 * 128 + l15;
#pragma unroll
      for (int nj = 0; nj < 8; ++nj) gp[nj * 16] = acc[mi][nj][r];
    }
}

// ---------------- mega GEMM: 8-phase-class schedule ----------------
// Tile: 256 rows x 32 cols x 8 groups, 512 threads = 8 waves (wave = 64r x 16c x 8g),
// BK=64 (2 kcT chunks), LDS = 2 x (32KB A + 32KB B) = 128KB, 1 block/CU.
// Per K-step: phase A {vmcnt(2); bar; ds_read A(8)+Bg0-3(8); issue A'+Bh0' (6);
// lgkmcnt(0); MFMA g0-3 (32)} ; phase B {vmcnt(6); bar; ds_read Bg4-7(8);
// issue Bh1' (2); lgkmcnt(0); MFMA g4-7 (32)}. vmcnt never drained mid-loop.
__global__ __launch_bounds__(512, 2) void k_mega(
    const float* __restrict__ c,
    const _Float16* __restrict__ Ahat, const _Float16* __restrict__ Bhat,
    const int* __restrict__ pos, const int* __restrict__ mask,
    const float* __restrict__ dc, const float* __restrict__ dWd,
    const float* __restrict__ bias,
    float* __restrict__ hout, float* __restrict__ cout) {
  __shared__ _Float16 As[2][16384];   // [buf][(kk*2+mb2)*4096 + slot*8]
  __shared__ _Float16 Bs[2][16384];   // [buf][kk*8192 + ghalf*4096 + ...]

  const int tid = threadIdx.x;        // 512
  const int id = blockIdx.x;          // 1024
  const int xcd = id & 7;
  const int loc = id >> 3;            // 0..127
  const int mt = xcd * 8 + (loc >> 4);  // 0..63 (per-XCD contiguous M-tiles)
  const int nT = loc & 15;
  const int m0 = mt * 256;
  const int n0 = nT * 32;
  const int bb = m0 >> 9;             // batch index (256-tile spans half a batch)

  const int lane = tid & 63, wid = tid >> 6;
  const int quad = lane >> 4, l15 = lane & 15;
  const int row_grp = wid >> 1;       // 0..3 -> rows [m0+row_grp*64, +64)
  const int col_half = wid & 1;       // 0..1 -> cols [n0+col_half*16, +16)
  const int mb2 = row_grp >> 1;       // which 128-row A-superblock half
  const int rg0 = (row_grp & 1) * 4;  // first 16-row group within superblock

  // A-frag base per kk: + mi*512 gives frag (rg0+mi)
  const int afoA0 = (mb2 * 4096) + ((rg0 * 4 + quad) * 16 + l15) * 8;        // kk=0
  const int afoA1 = (2 * 4096 + mb2 * 4096) + ((rg0 * 4 + quad) * 16 + l15) * 8; // kk=1
  // B-frag: kk*8192 + g*1024 + bfo
  const int bfo = col_half * 512 + quad * 128 + l15 * 8;

  f32x4 acc[8][4];
#pragma unroll
  for (int g = 0; g < 8; ++g)
#pragma unroll
    for (int mi = 0; mi < 4; ++mi) acc[g][mi] = (f32x4){0.f, 0.f, 0.f, 0.f};

  // stageA: A (4 superblocks, 8KB each, 1 load/thread) + B g0-3 halves (2 loads)
  auto stageA = [&](int buf, int kt2) {
    const int t = kt2 >> 3, kc2 = (kt2 & 7) * 2;
#pragma unroll
    for (int kk = 0; kk < 2; ++kk)
#pragma unroll
      for (int m2 = 0; m2 < 2; ++m2) {
        const int4* src = (const int4*)Ahat +
            ((size_t)((t * 128 + mt * 2 + m2) * 16 + kc2 + kk)) * 512;
        gl_lds16(src + tid, &As[buf][(kk * 2 + m2) * 4096 + tid * 8]);
      }
#pragma unroll
    for (int kk = 0; kk < 2; ++kk) {
      const int4* srcb = (const int4*)Bhat +
          ((size_t)((t * 16 + nT) * 16 + kc2 + kk)) * 1024;
      gl_lds16(srcb + tid, &Bs[buf][kk * 8192 + tid * 8]);
    }
  };
  // stageB: B g4-7 halves (2 loads)
  auto stageB = [&](int buf, int kt2) {
    const int t = kt2 >> 3, kc2 = (kt2 & 7) * 2;
#pragma unroll
    for (int kk = 0; kk < 2; ++kk) {
      const int4* srcb = (const int4*)Bhat +
          ((size_t)((t * 16 + nT) * 16 + kc2 + kk)) * 1024 + 512;
      gl_lds16(srcb + tid, &Bs[buf][kk * 8192 + 4096 + tid * 8]);
    }
  };

  // prologue: stage step 0 (FIFO order matches steady state: 6 then 2)
  stageA(0, 0);
  stageB(0, 0);

#pragma unroll 1
  for (int kt = 0; kt < 40; ++kt) {
    const int cur = kt & 1;
    const int nbuf = cur ^ 1;
    // ---- phase A: g0-3 ----
    VMCNT(2);                          // A(kt)+Bh0(kt) landed (own-wave)
    __builtin_amdgcn_s_barrier();      // all waves landed
    f16x8 a[4][2], b[4];
#pragma unroll
    for (int mi = 0; mi < 4; ++mi) {
      a[mi][0] = *(const f16x8*)&As[cur][afoA0 + mi * 512];
      a[mi][1] = *(const f16x8*)&As[cur][afoA1 + mi * 512];
    }
#pragma unroll
    for (int g = 0; g < 4; ++g) b[g] = *(const f16x8*)&Bs[cur][g * 1024 + bfo];
    if (kt < 39) stageA(nbuf, kt + 1);
    asm volatile("s_waitcnt lgkmcnt(0)" ::: "memory");
    __builtin_amdgcn_sched_barrier(0);
    __builtin_amdgcn_s_setprio(1);
#pragma unroll
    for (int g = 0; g < 4; ++g) {
#pragma unroll
      for (int mi = 0; mi < 4; ++mi)
        acc[g][mi] = __builtin_amdgcn_mfma_f32_16x16x32_f16(a[mi][0], b[g], acc[g][mi], 0, 0, 0);
    }
    // kk=1 B-frags for g0-3 (read now, after kk=0 MFMAs issued)
    f16x8 b1[4];
#pragma unroll
    for (int g = 0; g < 4; ++g) b1[g] = *(const f16x8*)&Bs[cur][8192 + g * 1024 + bfo];
    asm volatile("s_waitcnt lgkmcnt(0)" ::: "memory");
    __builtin_amdgcn_sched_barrier(0);
#pragma unroll
    for (int g = 0; g < 4; ++g) {
#pragma unroll
      for (int mi = 0; mi < 4; ++mi)
        acc[g][mi] = __builtin_amdgcn_mfma_f32_16x16x32_f16(a[mi][1], b1[g], acc[g][mi], 0, 0, 0);
    }
    __builtin_amdgcn_s_setprio(0);
    // ---- phase B: g4-7 ----
    if (kt < 39) { VMCNT(6); }         // Bh1(kt) landed (own-wave)
    else         { VMCNT(0); }
    __builtin_amdgcn_s_barrier();      // all waves landed; phase-A reads retired
    f16x8 c0[4], c1[4];
#pragma unroll
    for (int g = 0; g < 4; ++g) {
      c0[g] = *(const f16x8*)&Bs[cur][4096 + g * 1024 + bfo];
      c1[g] = *(const f16x8*)&Bs[cur][8192 + 4096 + g * 1024 + bfo];
    }
    if (kt < 39) stageB(nbuf, kt + 1);
    asm volatile("s_waitcnt lgkmcnt(0)" ::: "memory");
    __builtin_amdgcn_sched_barrier(0);
    __builtin_amdgcn_s_setprio(1);
#pragma unroll
    for (int g = 0; g < 4; ++g) {
#pragma unroll
      for (int mi = 0; mi < 4; ++mi)
        acc[4 + g][mi] = __builtin_amdgcn_mfma_f32_16x16x32_f16(a[mi][0], c0[g], acc[4 + g][mi], 0, 0, 0);
    }
#pragma unroll
    for (int g = 0; g < 4; ++g) {
#pragma unroll
      for (int mi = 0; mi < 4; ++mi)
        acc[4 + g][mi] = __builtin_amdgcn_mfma_f32_16x16x32_f16(a[mi][1], c1[g], acc[4 + g][mi], 0, 0, 0);
    }
    __builtin_amdgcn_s_setprio(0);
    __builtin_amdgcn_s_barrier();      // phase-B reads retired before next writes
  }

  // ---- fused epilogue (per thread: 16 rows x 1 col) ----
  const int col = n0 + col_half * 16 + l15;
  const float tdcv = dc[bb * Hn + col];
  float biasr[8], dwdr[8];
#pragma unroll
  for (int g = 0; g < 8; ++g) {
    biasr[g] = bias[g * Hn + col];
    dwdr[g] = dWd[((size_t)g * Bn + bb) * Hn + col];
  }

#pragma unroll
  for (int mi = 0; mi < 4; ++mi) {
#pragma unroll
    for (int r = 0; r < 4; ++r) {
      const int row = m0 + row_grp * 64 + mi * 16 + quad * 4 + r;
      const int srow = row & (Sn - 1);
      const float mf = (float)mask[row];
      const int pp = pos[row];
      const size_t rb = (size_t)row * Hn;
      float cf = c[rb + col];
      float cb = 0.f, ca = 0.f;
      if (srow >= 1) cb = c[rb - Hn + col];
      if (srow >= 2) cb += c[rb - 2 * Hn + col];
      if (srow <= Sn - 2) ca = c[rb + Hn + col];
      if (srow <= Sn - 3) ca += c[rb + 2 * Hn + col];
      float sw = pp ? c[((size_t)(bb * Sn + pp - 1)) * Hn + col] : 0.f;
      float z[8];
#pragma unroll
      for (int g = 0; g < 8; ++g)
        z[g] = acc[g][mi][r] + biasr[g] + dwdr[g];
      float e0 = __expf(sigf(z[0]));
      float e1 = __expf(sigf(z[1]));
      float e2 = __expf(sigf(z[2]));
      float e3 = __expf(sigf(z[3]));
      float e4 = __expf(sigf(z[4]));
      float e5 = __expf(sigf(z[5]));
      float inv = 1.f / (e0 + e1 + e2 + e3 + e4 + e5);
      float o = sigf(z[6]);
      float u = tanhf(z[7]);
      float cn = inv * (e0 * cb + e1 * ca + e2 * cf + e3 * tdcv + e4 * sw + e5 * u);
      cout[rb + col] = cn * mf;
      hout[rb + col] = o * tanhf(cn) * mf;
    }
  }
}

extern "C" void kernel_launch(void* const* d_in, const int* in_sizes, int n_in,
                              void* d_out, int out_size, void* d_ws, size_t ws_size,
                              hipStream_t stream) {
  (void)in_sizes; (void)n_in; (void)out_size; (void)ws_size;
  const float* word   = (const float*)d_in[0];
  const float* init_h = (const float*)d_in[1];
  const float* init_c = (const float*)d_in[2];
  const float* Wx     = (const float*)d_in[3];
  const float* Wh     = (const float*)d_in[4];
  const float* Wi     = (const float*)d_in[5];
  const float* Wdm    = (const float*)d_in[6];
  const float* Wsm    = (const float*)d_in[7];
  const float* bias   = (const float*)d_in[8];
  const float* gW     = (const float*)d_in[9];
  const float* gb     = (const float*)d_in[10];
  const int*   pos    = (const int*)d_in[11];
  const int*   mask   = (const int*)d_in[12];

  float* ws = (float*)d_ws;
  size_t off = 0;
  auto alloc = [&](size_t nel) { float* p = ws + off; off += nel; return p; };
  float* cA   = alloc(NHe);
  float* cB   = alloc(NHe);
  float* hS   = alloc(NHe);           // single h buffer; G aliases it (disjoint lifetimes)
  float* G    = hS;
  _Float16* Ahat = (_Float16*)alloc(5 * NHe / 2);          // 5 terms fp16, 84 MB
  _Float16* Bhat = (_Float16*)alloc(5 * 8 * 512 * 512 / 2); // 21 MB
  _Float16* Ghat = (_Float16*)alloc(512 * 512 / 2);         // 0.5 MB
  float* part = alloc(16 * Bn * Hn);
  float* np_  = alloc(8 * Bn * Hn);
  float* dp_  = alloc(8 * Bn * Hn);
  float* dh   = alloc(Bn * Hn);
  float* dc   = alloc(Bn * Hn);
  float* dh2  = alloc(Bn * Hn);
  float* dc2  = alloc(Bn * Hn);
  float* comb = alloc(Bn * Hn);
  float* gd   = alloc(Bn * Hn);
  float* go   = alloc(Bn * Hn);
  float* gfA  = alloc(Bn * Hn);
  float* dWd  = alloc(8 * Bn * Hn);
  // total ~ 209 MB

  dim3 blk(256);
  int g4 = (int)(NHe / 4 / 256);          // 8192 blocks
  int gbh = (Bn * Hn) / 256;              // 64 blocks

  k_convw<<<dim3(16, 16, 40), dim3(64), 0, stream>>>(Wx, Wh, Wsm, Wi, Bhat);
  k_convG<<<dim3(16, 4), blk, 0, stream>>>(gW, Ghat);
  k_prepW<<<dim3(128, 16), blk, 0, stream>>>(word, mask, Ahat);
  k_init<<<g4, blk, 0, stream>>>(init_h, init_c, mask, hS, cA);
  k_mean2<<<gbh, blk, 0, stream>>>(hS, cA, dh, dc);

  float* ccur = cA; float* cnxt = cB;
  for (int l = 0; l < NLAYER; ++l) {
    // NOTE: prepA + mean1a must consume hS BEFORE k_gemm1 overwrites it (G aliases hS)
    k_prepA<<<dim3(128, 16, 4), blk, 0, stream>>>(hS, pos, Ahat);
    k_mean1a<<<dim3(Bn, 8), blk, 0, stream>>>(hS, part);
    k_mean1b<<<16, blk, 0, stream>>>(part, comb);
    k_gates_small<<<gbh, blk, 0, stream>>>(dh, comb, gW, gb, gd, go, gfA);
    k_dWd<<<(8 * Bn * Hn) / 256, blk, 0, stream>>>(dh, Wdm, dWd);
    k_gemm1<<<dim3(128, 4), blk, 0, stream>>>(Ahat, Ghat, G);
    k_dummy1<<<dim3(Bn, 8), dim3(512), 0, stream>>>(G, gfA, ccur, mask, np_, dp_);
    k_dummy2<<<gbh, blk, 0, stream>>>(np_, dp_, gd, go, dc, dh2, dc2);

    float* hout = (l == NLAYER - 1) ? (float*)d_out : hS;
    k_mega<<<dim3(1024), dim3(512), 0, stream>>>(
        ccur, Ahat, Bhat, pos, mask, dc, dWd, bias, hout, cnxt);

    float* t1;
    t1 = ccur; ccur = cnxt; cnxt = t1;
    t1 = dh; dh = dh2; dh2 = t1;
    t1 = dc; dc = dc2; dc2 = t1;
  }
}

// Round 5
// 1883.594 us; speedup vs baseline: 2.4379x; 1.2084x over previous
//
#include <hip/hip_runtime.h>
#include <cstddef>

#define Bn 32
#define Sn 512
#define Hn 512
#define Rn (Bn*Sn)
#define NLAYER 4
constexpr size_t NHe = (size_t)Rn * Hn;   // 8,388,608 elements per (B,S,H) tensor

typedef __attribute__((ext_vector_type(8))) _Float16 f16x8;
typedef __attribute__((ext_vector_type(4))) float f32x4;

__device__ __forceinline__ float sigf(float x) { return 1.f / (1.f + __expf(-x)); }
// 16B global -> LDS DMA (lane-linear dest; LDS base is wave-uniform + lane*16)
__device__ __forceinline__ void gl_lds16(const void* g, void* l) {
  __builtin_amdgcn_global_load_lds((const __attribute__((address_space(1))) void*)g,
                                   (__attribute__((address_space(3))) void*)l, 16, 0, 0);
}
#define VMCNT(n) asm volatile("s_waitcnt vmcnt(" #n ")" ::: "memory")

// fp16 A-frag slot for M=32 operands (dh/comb): element (b,k) ->
// (((kcT*2+rg)*4+quad)*16+l15)*8 + j  with rg=b>>4,l15=b&15,kcT=k>>5,quad=(k>>3)&3,j=k&7
__device__ __forceinline__ int a32slot(int b, int k) {
  int kcT = k >> 5, quad = (k >> 3) & 3, j = k & 7, rg = b >> 4, l15 = b & 15;
  return ((((kcT * 2 + rg) * 4 + quad) * 16 + l15) * 8) + j;
}

// ---------------- init: h = init_h*m, c = init_c*m ----------------
__global__ void k_init(const float* __restrict__ ih, const float* __restrict__ ic,
                       const int* __restrict__ mask,
                       float* __restrict__ h, float* __restrict__ c) {
  size_t i = (size_t)blockIdx.x * blockDim.x + threadIdx.x;  // over NHe/4
  size_t n = i >> 7;
  float m = (float)mask[n];
  float4 b = ((const float4*)ih)[i];
  float4 d = ((const float4*)ic)[i];
  b.x *= m; b.y *= m; b.z *= m; b.w *= m;
  d.x *= m; d.y *= m; d.z *= m; d.w *= m;
  ((float4*)h)[i] = b; ((float4*)c)[i] = d;
}

// ---------------- mean2 (once): dh16 (frag fp16), dc ----------------
__global__ void k_mean2(const float* __restrict__ x, const float* __restrict__ y,
                        _Float16* __restrict__ dh16, float* __restrict__ oy) {
  int idx = blockIdx.x * blockDim.x + threadIdx.x;
  int b = idx >> 9, k = idx & 511;
  const float* px = x + (size_t)b * Sn * Hn + k;
  const float* py = y + (size_t)b * Sn * Hn + k;
  float sx = 0.f, sy = 0.f;
#pragma unroll 8
  for (int t = 0; t < Sn; ++t) { sx += px[(size_t)t * Hn]; sy += py[(size_t)t * Hn]; }
  oy[idx] = sy * (1.f / Sn);
  dh16[a32slot(b, k)] = (_Float16)(sx * (1.f / Sn));
}

// ---------------- mean over s: two-stage, float4 ----------------
__global__ void k_mean1a(const float* __restrict__ x, float* __restrict__ part) {
  int b = blockIdx.x, sc = blockIdx.y;          // 32 x 8
  int k4 = threadIdx.x & 127;                   // float4 over 512 k
  int so = threadIdx.x >> 7;                    // 0/1
  const float4* px = (const float4*)x + ((size_t)(b * Sn + sc * 64 + so)) * 128 + k4;
  float4 s = make_float4(0.f, 0.f, 0.f, 0.f);
#pragma unroll 4
  for (int t = 0; t < 32; ++t) {
    float4 v = px[(size_t)t * 256];
    s.x += v.x; s.y += v.y; s.z += v.z; s.w += v.w;
  }
  ((float4*)part)[((size_t)(sc * 2 + so) * Bn + b) * 128 + k4] = s;
}
__global__ void k_mean1b(const float* __restrict__ part, _Float16* __restrict__ comb16) {
  int idx = blockIdx.x * blockDim.x + threadIdx.x;   // B*H/4 = 4096
  int b = idx >> 7, k4 = idx & 127;
  float4 s = make_float4(0.f, 0.f, 0.f, 0.f);
#pragma unroll
  for (int p = 0; p < 16; ++p) {
    float4 v = ((const float4*)part)[((size_t)p * Bn + b) * 128 + k4];
    s.x += v.x; s.y += v.y; s.z += v.z; s.w += v.w;
  }
  float vv[4] = {s.x, s.y, s.z, s.w};
#pragma unroll
  for (int jj = 0; jj < 4; ++jj)
    comb16[a32slot(b, k4 * 4 + jj)] = (_Float16)(vv[jj] * (1.f / Sn));
}

// ---------------- small-GEMM weight pre-swizzle (once): gW0..4 + Wd0..7 ----------------
// Shat superblock sb = ((mat*4 + nT4)*16 + kcT)*4096 halfs.
// Interior ((nj*4+quad)*16+l15)*8+j ; element k=kcT*32+quad*8+j, n=nT4*128+nj*16+l15
__global__ void k_convS(const float* __restrict__ gW, const float* __restrict__ Wd,
                        _Float16* __restrict__ Shat) {
  int kcT = blockIdx.x, nT4 = blockIdx.y, mat = blockIdx.z;  // 16,4,13
  int tid = threadIdx.x;  // 256
  const float* w = (mat < 5) ? (gW + (size_t)mat * 262144)
                             : (Wd + (size_t)(mat - 5) * 262144);
  size_t sb = ((size_t)((mat * 4 + nT4) * 16 + kcT)) * 4096;
#pragma unroll
  for (int half = 0; half < 2; ++half) {
    int st = half * 256 + tid;             // slot 0..511
    int nj = st >> 6, quad = (st >> 4) & 3, l15 = st & 15;
    int n = nT4 * 128 + nj * 16 + l15;
    int k0 = kcT * 32 + quad * 8;
    f16x8 w8;
#pragma unroll
    for (int j = 0; j < 8; ++j) w8[j] = (_Float16)w[(size_t)(k0 + j) * Hn + n];
    *(f16x8*)&Shat[sb + (size_t)st * 8] = w8;
  }
}

// ---------------- k_small: 13 batched M=32 GEMMs via MFMA (LDS-free) ----------------
// mats 0..4 -> s0..s4 (A: dh,comb,dh,comb,dh); mats 5..12 -> dWd g0..7 (A: dh).
// Output S[mat][b][col] f32 (mat stride 16384).
__global__ __launch_bounds__(256) void k_small(const _Float16* __restrict__ dh16,
                                               const _Float16* __restrict__ comb16,
                                               const _Float16* __restrict__ Shat,
                                               float* __restrict__ S) {
  const int mat = blockIdx.x, nT4 = blockIdx.y;  // 13, 4
  const int tid = threadIdx.x;
  const int lane = tid & 63, wid = tid >> 6;
  const int quad = lane >> 4, l15 = lane & 15;
  const _Float16* A16 = (mat == 1 || mat == 3) ? comb16 : dh16;
  const _Float16* Sb = Shat + ((size_t)((mat * 4 + nT4) * 16)) * 4096;

  f32x4 acc[2][2];
#pragma unroll
  for (int rg = 0; rg < 2; ++rg)
#pragma unroll
    for (int nj = 0; nj < 2; ++nj) acc[rg][nj] = (f32x4){0.f, 0.f, 0.f, 0.f};

#pragma unroll 4
  for (int kcT = 0; kcT < 16; ++kcT) {
    f16x8 a0 = *(const f16x8*)&A16[(((kcT * 2 + 0) * 4 + quad) * 16 + l15) * 8];
    f16x8 a1 = *(const f16x8*)&A16[(((kcT * 2 + 1) * 4 + quad) * 16 + l15) * 8];
    f16x8 b0 = *(const f16x8*)&Sb[(size_t)kcT * 4096 + (((wid * 2 + 0) * 4 + quad) * 16 + l15) * 8];
    f16x8 b1 = *(const f16x8*)&Sb[(size_t)kcT * 4096 + (((wid * 2 + 1) * 4 + quad) * 16 + l15) * 8];
    acc[0][0] = __builtin_amdgcn_mfma_f32_16x16x32_f16(a0, b0, acc[0][0], 0, 0, 0);
    acc[0][1] = __builtin_amdgcn_mfma_f32_16x16x32_f16(a0, b1, acc[0][1], 0, 0, 0);
    acc[1][0] = __builtin_amdgcn_mfma_f32_16x16x32_f16(a1, b0, acc[1][0], 0, 0, 0);
    acc[1][1] = __builtin_amdgcn_mfma_f32_16x16x32_f16(a1, b1, acc[1][1], 0, 0, 0);
  }
#pragma unroll
  for (int rg = 0; rg < 2; ++rg)
#pragma unroll
    for (int nj = 0; nj < 2; ++nj)
#pragma unroll
      for (int r = 0; r < 4; ++r) {
        int brow = rg * 16 + quad * 4 + r;
        int col = nT4 * 128 + (wid * 2 + nj) * 16 + l15;
        S[(size_t)mat * 16384 + brow * 512 + col] = acc[rg][nj][r];
      }
}

// ---------------- gates combine: gd, go, gfA from S ----------------
__global__ void k_gates2(const float* __restrict__ S, const float* __restrict__ gb,
                         float* __restrict__ gd, float* __restrict__ go,
                         float* __restrict__ gfA) {
  int idx = blockIdx.x * blockDim.x + threadIdx.x;  // B*H = 16384
  int k = idx & 511;
  gd[idx] = sigf(S[idx] + S[16384 + idx] + gb[k]);
  go[idx] = sigf(S[2 * 16384 + idx] + S[3 * 16384 + idx] + gb[512 + k]);
  gfA[idx] = S[4 * 16384 + idx] + gb[1024 + k];
}

// ---------------- dummy combine: reads gemm1d partials ----------------
__global__ void k_dummy2(const float* __restrict__ pnum, const float* __restrict__ pden,
                         const float* __restrict__ gd, const float* __restrict__ go,
                         const float* __restrict__ dc,
                         _Float16* __restrict__ dh16o, float* __restrict__ dc2) {
  int idx = blockIdx.x * blockDim.x + threadIdx.x;  // B*H
  int b = idx >> 9, k = idx & 511;
  float ed = __expf(gd[idx]);
  float num = ed * dc[idx], den = ed;
#pragma unroll
  for (int q = 0; q < 4; ++q) {
    num += pnum[(size_t)(b * 4 + q) * 512 + k];
    den += pden[(size_t)(b * 4 + q) * 512 + k];
  }
  float d = num / den;
  dc2[idx] = d;
  dh16o[a32slot(b, k)] = (_Float16)(go[idx] * tanhf(d));
}

// ---------------- weight pre-swizzle: f32 [g][k][n] -> fp16 frag-order superblocks ----------------
// Bhat superblock sb = (t*16 + nT)*16 + kcT, 8192 halfs (16KB) each.
// Interior: (((g*2 + ni)*4 + quad)*16 + l15)*8 + j ; element k=kcT*32+quad*8+j, n=nT*32+ni*16+l15
__global__ void k_convw(const float* __restrict__ Wx, const float* __restrict__ Wh,
                        const float* __restrict__ Wsm, const float* __restrict__ Wi,
                        _Float16* __restrict__ Bhat) {
  int kcT = blockIdx.x, nT = blockIdx.y, tg = blockIdx.z;  // 16,16,40
  int t = tg >> 3, g = tg & 7;
  const float* base;
  if (t == 0)      base = Wx  + (size_t)g * 262144;
  else if (t == 1) base = Wh  + (size_t)g * 524288;
  else if (t == 2) base = Wh  + (size_t)g * 524288 + 262144;
  else if (t == 3) base = Wsm + (size_t)g * 262144;
  else             base = Wi  + (size_t)g * 262144;
  size_t sbase = ((size_t)(t * 16 + nT) * 16 + kcT) * 8192 + (size_t)g * 1024;
  int lane = threadIdx.x;  // 64 threads
  for (int cch = lane; cch < 128; cch += 64) {
    int ni = cch >> 6, quad = (cch >> 4) & 3, l15 = cch & 15;
    int n = nT * 32 + ni * 16 + l15;
    int k0 = kcT * 32 + quad * 8;
    f16x8 w8;
#pragma unroll
    for (int j = 0; j < 8; ++j) w8[j] = (_Float16)base[(size_t)(k0 + j) * Hn + n];
    *(f16x8*)&Bhat[sbase + (size_t)cch * 8] = w8;
  }
}

// ---------------- gWhf pre-swizzle (once): superblock (nT4*16+kcT), 4096 halfs ----------------
__global__ void k_convG(const float* __restrict__ gW, _Float16* __restrict__ Ghat) {
  int kcT = blockIdx.x, nT4 = blockIdx.y;  // 16, 4
  int tid = threadIdx.x;                   // 256
  const float* w = gW + (size_t)5 * Hn * Hn;
  size_t sb = ((size_t)(nT4 * 16 + kcT)) * 4096;
#pragma unroll
  for (int half = 0; half < 2; ++half) {
    int st = half * 256 + tid;             // slot 0..511
    int nj = st >> 6, quad = (st >> 4) & 3, l15 = st & 15;
    int n = nT4 * 128 + nj * 16 + l15;
    int k0 = kcT * 32 + quad * 8;
    f16x8 w8;
#pragma unroll
    for (int j = 0; j < 8; ++j) w8[j] = (_Float16)w[(size_t)(k0 + j) * Hn + n];
    *(f16x8*)&Ghat[sb + (size_t)st * 8] = w8;
  }
}

// ---------------- A pre-convert per layer: ALL terms 0..3 in one pass ----------------
// Ahat superblock sb = (t*128 + mb)*16 + kcT, 4096 halfs (8KB).
// Interior slot st = (rg*4 + quad)*16 + l15 ; element row=mb*128+rg*16+l15, k=kcT*32+quad*8+j
__global__ void k_prepAll(const float* __restrict__ h, const int* __restrict__ pos,
                          _Float16* __restrict__ Ahat) {
  const int mb = blockIdx.x, kcT = blockIdx.y;  // 128,16
  const int tid = threadIdx.x;  // 256
#pragma unroll
  for (int half = 0; half < 2; ++half) {
    int st = half * 256 + tid;
    int rg = st >> 6, quad = (st >> 4) & 3, l15 = st & 15;
    int r = mb * 128 + rg * 16 + l15;
    int srow = r & (Sn - 1);
    int k0 = kcT * 32 + quad * 8;
    const float* base = h + (size_t)r * Hn + k0;
    float v0[8], v1[8], v2[8], v3[8];
#pragma unroll
    for (int j = 0; j < 8; ++j) { v0[j] = base[j]; v1[j] = 0.f; v2[j] = 0.f; v3[j] = 0.f; }
    if (srow >= 1) { const float* p = base - Hn;
#pragma unroll
      for (int j = 0; j < 8; ++j) v1[j] += p[j]; }
    if (srow >= 2) { const float* p = base - 2 * Hn;
#pragma unroll
      for (int j = 0; j < 8; ++j) v1[j] += p[j]; }
    if (srow <= Sn - 2) { const float* p = base + Hn;
#pragma unroll
      for (int j = 0; j < 8; ++j) v2[j] += p[j]; }
    if (srow <= Sn - 3) { const float* p = base + 2 * Hn;
#pragma unroll
      for (int j = 0; j < 8; ++j) v2[j] += p[j]; }
    int pp = pos[r];
    if (pp) {
      const float* p = h + ((size_t)((r >> 9) * Sn + pp - 1)) * Hn + k0;
#pragma unroll
      for (int j = 0; j < 8; ++j) v3[j] = p[j];
    }
    size_t stoff = (size_t)st * 8;
    f16x8 o0, o1, o2, o3;
#pragma unroll
    for (int j = 0; j < 8; ++j) {
      o0[j] = (_Float16)v0[j]; o1[j] = (_Float16)v1[j];
      o2[j] = (_Float16)v2[j]; o3[j] = (_Float16)v3[j];
    }
    *(f16x8*)&Ahat[((size_t)(0 * 128 + mb) * 16 + kcT) * 4096 + stoff] = o0;
    *(f16x8*)&Ahat[((size_t)(1 * 128 + mb) * 16 + kcT) * 4096 + stoff] = o1;
    *(f16x8*)&Ahat[((size_t)(2 * 128 + mb) * 16 + kcT) * 4096 + stoff] = o2;
    *(f16x8*)&Ahat[((size_t)(3 * 128 + mb) * 16 + kcT) * 4096 + stoff] = o3;
  }
}

// word term (t=4): layer-invariant, run once
__global__ void k_prepW(const float* __restrict__ w, const int* __restrict__ mask,
                        _Float16* __restrict__ Ahat) {
  const int mb = blockIdx.x, kcT = blockIdx.y;  // 128,16
  const int tid = threadIdx.x;
  size_t sb = ((size_t)(4 * 128 + mb) * 16 + kcT) * 4096;
#pragma unroll
  for (int half = 0; half < 2; ++half) {
    int st = half * 256 + tid;
    int rg = st >> 6, quad = (st >> 4) & 3, l15 = st & 15;
    int r = mb * 128 + rg * 16 + l15;
    int k0 = kcT * 32 + quad * 8;
    float mf = (float)mask[r];
    const float* base = w + (size_t)r * Hn + k0;
    f16x8 o8;
#pragma unroll
    for (int j = 0; j < 8; ++j) o8[j] = (_Float16)(base[j] * mf);
    *(f16x8*)&Ahat[sb + (size_t)st * 8] = o8;
  }
}

// ---------------- G-GEMM fused with dummy-softmax partial reduction ----------------
// Computes G = h @ gWhf tile (128x128), applies e = mask*exp(sig(G+gfa)), reduces
// num/den over the tile's 128 rows -> pnum/pden[mb][col]. G never materialized.
__global__ __launch_bounds__(256, 2) void k_gemm1d(const _Float16* __restrict__ Ahat,
                                                   const _Float16* __restrict__ Ghat,
                                                   const float* __restrict__ gfA,
                                                   const float* __restrict__ cbuf,
                                                   const int* __restrict__ mask,
                                                   float* __restrict__ pnum,
                                                   float* __restrict__ pden) {
  __shared__ _Float16 As[2][4096];
  __shared__ _Float16 Bs[2][4096];
  __shared__ float red[4][2][128];
  const int tid = threadIdx.x;
  const int mb = blockIdx.x, nT4 = blockIdx.y;
  const int lane = tid & 63, wid = tid >> 6;
  const int quad = lane >> 4, l15 = lane & 15;
  const int afo0 = (((wid * 2 + 0) * 4 + quad) * 16 + l15) * 8;
  const int afo1 = (((wid * 2 + 1) * 4 + quad) * 16 + l15) * 8;

  f32x4 acc[2][8];
#pragma unroll
  for (int mi = 0; mi < 2; ++mi)
#pragma unroll
    for (int nj = 0; nj < 8; ++nj) acc[mi][nj] = (f32x4){0.f, 0.f, 0.f, 0.f};

  auto stage = [&](int buf, int kcT) {
    const int4* sa = (const int4*)Ahat + ((size_t)(mb * 16 + kcT) << 9);
    const int4* sbp = (const int4*)Ghat + ((size_t)(nT4 * 16 + kcT) << 9);
#pragma unroll
    for (int q = 0; q < 2; ++q) {
      gl_lds16(sa + q * 256 + tid, &As[buf][(q * 256 + tid) * 8]);
      gl_lds16(sbp + q * 256 + tid, &Bs[buf][(q * 256 + tid) * 8]);
    }
  };

  stage(0, 0);
  __syncthreads();
#pragma unroll 1
  for (int kcT = 0; kcT < 16; ++kcT) {
    const int cur = kcT & 1;
    if (kcT < 15) stage(cur ^ 1, kcT + 1);
    f16x8 a0 = *(const f16x8*)&As[cur][afo0];
    f16x8 a1 = *(const f16x8*)&As[cur][afo1];
#pragma unroll
    for (int nj = 0; nj < 8; ++nj) {
      f16x8 bh = *(const f16x8*)&Bs[cur][((nj * 4 + quad) * 16 + l15) * 8];
      acc[0][nj] = __builtin_amdgcn_mfma_f32_16x16x32_f16(a0, bh, acc[0][nj], 0, 0, 0);
      acc[1][nj] = __builtin_amdgcn_mfma_f32_16x16x32_f16(a1, bh, acc[1][nj], 0, 0, 0);
    }
    __syncthreads();
  }

  // ---- fused dummy-softmax partial epilogue ----
  const int bb = mb >> 2;
  float gfa[8], nsum[8], dsum[8];
#pragma unroll
  for (int nj = 0; nj < 8; ++nj) {
    gfa[nj] = gfA[bb * 512 + nT4 * 128 + nj * 16 + l15];
    nsum[nj] = 0.f; dsum[nj] = 0.f;
  }
#pragma unroll
  for (int mi = 0; mi < 2; ++mi) {
#pragma unroll
    for (int r = 0; r < 4; ++r) {
      int row = mb * 128 + wid * 32 + mi * 16 + quad * 4 + r;
      float mf = (float)mask[row];
      const float* crow = cbuf + (size_t)row * 512 + nT4 * 128 + l15;
#pragma unroll
      for (int nj = 0; nj < 8; ++nj) {
        float e = __expf(sigf(acc[mi][nj][r] + gfa[nj])) * mf;
        nsum[nj] += e * crow[nj * 16];
        dsum[nj] += e;
      }
    }
  }
#pragma unroll
  for (int nj = 0; nj < 8; ++nj) {
    nsum[nj] += __shfl_xor(nsum[nj], 16);
    nsum[nj] += __shfl_xor(nsum[nj], 32);
    dsum[nj] += __shfl_xor(dsum[nj], 16);
    dsum[nj] += __shfl_xor(dsum[nj], 32);
  }
  if (quad == 0) {
#pragma unroll
    for (int nj = 0; nj < 8; ++nj) {
      red[wid][0][nj * 16 + l15] = nsum[nj];
      red[wid][1][nj * 16 + l15] = dsum[nj];
    }
  }
  __syncthreads();
  {
    int cc = tid & 127, which = tid >> 7;   // 256 threads -> 2 x 128
    float v = red[0][which][cc] + red[1][which][cc] + red[2][which][cc] + red[3][which][cc];
    float* dst = which ? pden : pnum;
    dst[(size_t)mb * 512 + nT4 * 128 + cc] = v;
  }
}

// ---------------- mega GEMM: 8-phase-class schedule (unchanged from r4) ----------------
__global__ __launch_bounds__(512, 2) void k_mega(
    const float* __restrict__ c,
    const _Float16* __restrict__ Ahat, const _Float16* __restrict__ Bhat,
    const int* __restrict__ pos, const int* __restrict__ mask,
    const float* __restrict__ dc, const float* __restrict__ dWd,
    const float* __restrict__ bias,
    float* __restrict__ hout, float* __restrict__ cout) {
  __shared__ _Float16 As[2][16384];   // [buf][(kk*2+mb2)*4096 + slot*8]
  __shared__ _Float16 Bs[2][16384];   // [buf][kk*8192 + ghalf*4096 + ...]

  const int tid = threadIdx.x;        // 512
  const int id = blockIdx.x;          // 1024
  const int xcd = id & 7;
  const int loc = id >> 3;            // 0..127
  const int mt = xcd * 8 + (loc >> 4);  // 0..63 (per-XCD contiguous M-tiles)
  const int nT = loc & 15;
  const int m0 = mt * 256;
  const int n0 = nT * 32;
  const int bb = m0 >> 9;             // batch index

  const int lane = tid & 63, wid = tid >> 6;
  const int quad = lane >> 4, l15 = lane & 15;
  const int row_grp = wid >> 1;       // 0..3 -> rows [m0+row_grp*64, +64)
  const int col_half = wid & 1;       // 0..1 -> cols [n0+col_half*16, +16)
  const int mb2 = row_grp >> 1;
  const int rg0 = (row_grp & 1) * 4;

  const int afoA0 = (mb2 * 4096) + ((rg0 * 4 + quad) * 16 + l15) * 8;
  const int afoA1 = (2 * 4096 + mb2 * 4096) + ((rg0 * 4 + quad) * 16 + l15) * 8;
  const int bfo = col_half * 512 + quad * 128 + l15 * 8;

  f32x4 acc[8][4];
#pragma unroll
  for (int g = 0; g < 8; ++g)
#pragma unroll
    for (int mi = 0; mi < 4; ++mi) acc[g][mi] = (f32x4){0.f, 0.f, 0.f, 0.f};

  auto stageA = [&](int buf, int kt2) {
    const int t = kt2 >> 3, kc2 = (kt2 & 7) * 2;
#pragma unroll
    for (int kk = 0; kk < 2; ++kk)
#pragma unroll
      for (int m2 = 0; m2 < 2; ++m2) {
        const int4* src = (const int4*)Ahat +
            ((size_t)((t * 128 + mt * 2 + m2) * 16 + kc2 + kk)) * 512;
        gl_lds16(src + tid, &As[buf][(kk * 2 + m2) * 4096 + tid * 8]);
      }
#pragma unroll
    for (int kk = 0; kk < 2; ++kk) {
      const int4* srcb = (const int4*)Bhat +
          ((size_t)((t * 16 + nT) * 16 + kc2 + kk)) * 1024;
      gl_lds16(srcb + tid, &Bs[buf][kk * 8192 + tid * 8]);
    }
  };
  auto stageB = [&](int buf, int kt2) {
    const int t = kt2 >> 3, kc2 = (kt2 & 7) * 2;
#pragma unroll
    for (int kk = 0; kk < 2; ++kk) {
      const int4* srcb = (const int4*)Bhat +
          ((size_t)((t * 16 + nT) * 16 + kc2 + kk)) * 1024 + 512;
      gl_lds16(srcb + tid, &Bs[buf][kk * 8192 + 4096 + tid * 8]);
    }
  };

  stageA(0, 0);
  stageB(0, 0);

#pragma unroll 1
  for (int kt = 0; kt < 40; ++kt) {
    const int cur = kt & 1;
    const int nbuf = cur ^ 1;
    // ---- phase A: g0-3 ----
    VMCNT(2);
    __builtin_amdgcn_s_barrier();
    f16x8 a[4][2], b[4];
#pragma unroll
    for (int mi = 0; mi < 4; ++mi) {
      a[mi][0] = *(const f16x8*)&As[cur][afoA0 + mi * 512];
      a[mi][1] = *(const f16x8*)&As[cur][afoA1 + mi * 512];
    }
#pragma unroll
    for (int g = 0; g < 4; ++g) b[g] = *(const f16x8*)&Bs[cur][g * 1024 + bfo];
    if (kt < 39) stageA(nbuf, kt + 1);
    asm volatile("s_waitcnt lgkmcnt(0)" ::: "memory");
    __builtin_amdgcn_sched_barrier(0);
    __builtin_amdgcn_s_setprio(1);
#pragma unroll
    for (int g = 0; g < 4; ++g) {
#pragma unroll
      for (int mi = 0; mi < 4; ++mi)
        acc[g][mi] = __builtin_amdgcn_mfma_f32_16x16x32_f16(a[mi][0], b[g], acc[g][mi], 0, 0, 0);
    }
    f16x8 b1[4];
#pragma unroll
    for (int g = 0; g < 4; ++g) b1[g] = *(const f16x8*)&Bs[cur][8192 + g * 1024 + bfo];
    asm volatile("s_waitcnt lgkmcnt(0)" ::: "memory");
    __builtin_amdgcn_sched_barrier(0);
#pragma unroll
    for (int g = 0; g < 4; ++g) {
#pragma unroll
      for (int mi = 0; mi < 4; ++mi)
        acc[g][mi] = __builtin_amdgcn_mfma_f32_16x16x32_f16(a[mi][1], b1[g], acc[g][mi], 0, 0, 0);
    }
    __builtin_amdgcn_s_setprio(0);
    // ---- phase B: g4-7 ----
    if (kt < 39) { VMCNT(6); }
    else         { VMCNT(0); }
    __builtin_amdgcn_s_barrier();
    f16x8 c0[4], c1[4];
#pragma unroll
    for (int g = 0; g < 4; ++g) {
      c0[g] = *(const f16x8*)&Bs[cur][4096 + g * 1024 + bfo];
      c1[g] = *(const f16x8*)&Bs[cur][8192 + 4096 + g * 1024 + bfo];
    }
    if (kt < 39) stageB(nbuf, kt + 1);
    asm volatile("s_waitcnt lgkmcnt(0)" ::: "memory");
    __builtin_amdgcn_sched_barrier(0);
    __builtin_amdgcn_s_setprio(1);
#pragma unroll
    for (int g = 0; g < 4; ++g) {
#pragma unroll
      for (int mi = 0; mi < 4; ++mi)
        acc[4 + g][mi] = __builtin_amdgcn_mfma_f32_16x16x32_f16(a[mi][0], c0[g], acc[4 + g][mi], 0, 0, 0);
    }
#pragma unroll
    for (int g = 0; g < 4; ++g) {
#pragma unroll
      for (int mi = 0; mi < 4; ++mi)
        acc[4 + g][mi] = __builtin_amdgcn_mfma_f32_16x16x32_f16(a[mi][1], c1[g], acc[4 + g][mi], 0, 0, 0);
    }
    __builtin_amdgcn_s_setprio(0);
    __builtin_amdgcn_s_barrier();
  }

  // ---- fused epilogue (per thread: 16 rows x 1 col) ----
  const int col = n0 + col_half * 16 + l15;
  const float tdcv = dc[bb * Hn + col];
  float biasr[8], dwdr[8];
#pragma unroll
  for (int g = 0; g < 8; ++g) {
    biasr[g] = bias[g * Hn + col];
    dwdr[g] = dWd[((size_t)g * Bn + bb) * Hn + col];
  }

#pragma unroll
  for (int mi = 0; mi < 4; ++mi) {
#pragma unroll
    for (int r = 0; r < 4; ++r) {
      const int row = m0 + row_grp * 64 + mi * 16 + quad * 4 + r;
      const int srow = row & (Sn - 1);
      const float mf = (float)mask[row];
      const int pp = pos[row];
      const size_t rb = (size_t)row * Hn;
      float cf = c[rb + col];
      float cb = 0.f, ca = 0.f;
      if (srow >= 1) cb = c[rb - Hn + col];
      if (srow >= 2) cb += c[rb - 2 * Hn + col];
      if (srow <= Sn - 2) ca = c[rb + Hn + col];
      if (srow <= Sn - 3) ca += c[rb + 2 * Hn + col];
      float sw = pp ? c[((size_t)(bb * Sn + pp - 1)) * Hn + col] : 0.f;
      float z[8];
#pragma unroll
      for (int g = 0; g < 8; ++g)
        z[g] = acc[g][mi][r] + biasr[g] + dwdr[g];
      float e0 = __expf(sigf(z[0]));
      float e1 = __expf(sigf(z[1]));
      float e2 = __expf(sigf(z[2]));
      float e3 = __expf(sigf(z[3]));
      float e4 = __expf(sigf(z[4]));
      float e5 = __expf(sigf(z[5]));
      float inv = 1.f / (e0 + e1 + e2 + e3 + e4 + e5);
      float o = sigf(z[6]);
      float u = tanhf(z[7]);
      float cn = inv * (e0 * cb + e1 * ca + e2 * cf + e3 * tdcv + e4 * sw + e5 * u);
      cout[rb + col] = cn * mf;
      hout[rb + col] = o * tanhf(cn) * mf;
    }
  }
}

extern "C" void kernel_launch(void* const* d_in, const int* in_sizes, int n_in,
                              void* d_out, int out_size, void* d_ws, size_t ws_size,
                              hipStream_t stream) {
  (void)in_sizes; (void)n_in; (void)out_size; (void)ws_size;
  const float* word   = (const float*)d_in[0];
  const float* init_h = (const float*)d_in[1];
  const float* init_c = (const float*)d_in[2];
  const float* Wx     = (const float*)d_in[3];
  const float* Wh     = (const float*)d_in[4];
  const float* Wi     = (const float*)d_in[5];
  const float* Wdm    = (const float*)d_in[6];
  const float* Wsm    = (const float*)d_in[7];
  const float* bias   = (const float*)d_in[8];
  const float* gW     = (const float*)d_in[9];
  const float* gb     = (const float*)d_in[10];
  const int*   pos    = (const int*)d_in[11];
  const int*   mask   = (const int*)d_in[12];

  float* ws = (float*)d_ws;
  size_t off = 0;
  auto alloc = [&](size_t nel) { float* p = ws + off; off += nel; return p; };
  float* cA   = alloc(NHe);
  float* cB   = alloc(NHe);
  float* hS   = alloc(NHe);
  _Float16* Ahat = (_Float16*)alloc(5 * NHe / 2);           // 84 MB
  _Float16* Bhat = (_Float16*)alloc(5 * 8 * 512 * 512 / 2); // 21 MB
  _Float16* Ghat = (_Float16*)alloc(512 * 512 / 2);         // 0.5 MB
  _Float16* Shat = (_Float16*)alloc(13 * 512 * 512 / 2);    // 6.8 MB
  float* S    = alloc(13 * 16384);                          // 0.85 MB
  float* part = alloc(16 * Bn * Hn);
  float* pnum = alloc(128 * 512);
  float* pden = alloc(128 * 512);
  _Float16* dh16A = (_Float16*)alloc(8192);
  _Float16* dh16B = (_Float16*)alloc(8192);
  _Float16* comb16 = (_Float16*)alloc(8192);
  float* dc   = alloc(Bn * Hn);
  float* dc2  = alloc(Bn * Hn);
  float* gd   = alloc(Bn * Hn);
  float* go   = alloc(Bn * Hn);
  float* gfA  = alloc(Bn * Hn);
  // total ~ 217 MB

  dim3 blk(256);
  int g4 = (int)(NHe / 4 / 256);          // 8192 blocks
  int gbh = (Bn * Hn) / 256;              // 64 blocks

  k_convw<<<dim3(16, 16, 40), dim3(64), 0, stream>>>(Wx, Wh, Wsm, Wi, Bhat);
  k_convG<<<dim3(16, 4), blk, 0, stream>>>(gW, Ghat);
  k_convS<<<dim3(16, 4, 13), blk, 0, stream>>>(gW, Wdm, Shat);
  k_prepW<<<dim3(128, 16), blk, 0, stream>>>(word, mask, Ahat);
  k_init<<<g4, blk, 0, stream>>>(init_h, init_c, mask, hS, cA);
  k_mean2<<<gbh, blk, 0, stream>>>(hS, cA, dh16A, dc);

  float* ccur = cA; float* cnxt = cB;
  _Float16* dhc = dh16A; _Float16* dhn = dh16B;
  for (int l = 0; l < NLAYER; ++l) {
    k_prepAll<<<dim3(128, 16), blk, 0, stream>>>(hS, pos, Ahat);
    k_mean1a<<<dim3(Bn, 8), blk, 0, stream>>>(hS, part);
    k_mean1b<<<16, blk, 0, stream>>>(part, comb16);
    k_small<<<dim3(13, 4), blk, 0, stream>>>(dhc, comb16, Shat, S);
    k_gates2<<<gbh, blk, 0, stream>>>(S, gb, gd, go, gfA);
    k_gemm1d<<<dim3(128, 4), blk, 0, stream>>>(Ahat, Ghat, gfA, ccur, mask, pnum, pden);
    k_dummy2<<<gbh, blk, 0, stream>>>(pnum, pden, gd, go, dc, dhn, dc2);

    float* hout = (l == NLAYER - 1) ? (float*)d_out : hS;
    k_mega<<<dim3(1024), dim3(512), 0, stream>>>(
        ccur, Ahat, Bhat, pos, mask, dc, S + (size_t)5 * 16384, bias, hout, cnxt);

    float* t1;
    t1 = ccur; ccur = cnxt; cnxt = t1;
    t1 = dc; dc = dc2; dc2 = t1;
    _Float16* t2 = dhc; dhc = dhn; dhn = t2;
  }
}